// Round 1
// baseline (21980.099 us; speedup 1.0000x reference)
//
#include <hip/hip_runtime.h>
#include <hip/hip_bf16.h>
#include <math.h>

#define D_    1024
#define H_    16
#define HD_   64
#define L_    14
#define FF_   4096
#define T_    768
#define NPOS_ (2*T_-1)   // 1535

// ---------------- reduction helpers ----------------
__device__ inline float waveRedSum(float v) {
#pragma unroll
  for (int o = 32; o > 0; o >>= 1) v += __shfl_down(v, o, 64);
  return v;
}
__device__ inline float waveRedMax(float v) {
#pragma unroll
  for (int o = 32; o > 0; o >>= 1) v = fmaxf(v, __shfl_down(v, o, 64));
  return v;
}
// 256-thread block reductions; sh must have >= 8 floats. Safe to call repeatedly.
__device__ inline float blockRedSum(float v, float* sh) {
  int lane = threadIdx.x & 63, wid = threadIdx.x >> 6;
  v = waveRedSum(v);
  if (lane == 0) sh[wid] = v;
  __syncthreads();
  if (wid == 0) {
    float x = (lane < 4) ? sh[lane] : 0.f;
    x = waveRedSum(x);
    if (lane == 0) sh[0] = x;
  }
  __syncthreads();
  float r = sh[0];
  __syncthreads();
  return r;
}
__device__ inline float blockRedMax(float v, float* sh) {
  int lane = threadIdx.x & 63, wid = threadIdx.x >> 6;
  v = waveRedMax(v);
  if (lane == 0) sh[wid] = v;
  __syncthreads();
  if (wid == 0) {
    float x = (lane < 4) ? sh[lane] : -1e30f;
    x = waveRedMax(x);
    if (lane == 0) sh[0] = x;
  }
  __syncthreads();
  float r = sh[0];
  __syncthreads();
  return r;
}

// ---------------- LayerNorm (one block per row, D_=1024) ----------------
__global__ __launch_bounds__(256) void ln_kernel(
    const float* __restrict__ x, const float* __restrict__ g,
    const float* __restrict__ b, float* __restrict__ y,
    float eps, int relu, float scale)
{
  __shared__ float sh[8];
  long row = blockIdx.x;
  const float* xr = x + row * D_;
  float* yr = y + row * D_;
  float s = 0.f;
  for (int i = threadIdx.x; i < D_; i += 256) s += xr[i];
  float mean = blockRedSum(s, sh) * (1.f / D_);
  float vs = 0.f;
  for (int i = threadIdx.x; i < D_; i += 256) { float d = xr[i] - mean; vs += d * d; }
  float var = blockRedSum(vs, sh) * (1.f / D_);
  float inv = rsqrtf(var + eps);
  for (int i = threadIdx.x; i < D_; i += 256) {
    float v = (xr[i] - mean) * inv * g[i] + b[i];
    if (relu) v = fmaxf(v, 0.f);
    yr[i] = v * scale;
  }
}

// ---------------- generic fp32 GEMM: C = A@B (+bias)(+resid)(relu) ----------------
// 64x64 tile, BK=16, 256 threads, 4x4 per thread. K must be a multiple of 16.
#define BM 64
#define BN 64
#define BK 16
__global__ __launch_bounds__(256) void gemm_kernel(
    const float* __restrict__ A, int lda, long sA,
    const float* __restrict__ B, int ldb, long sB,
    float* __restrict__ C, int ldc, long sC,
    const float* __restrict__ bias,
    const float* __restrict__ resid, int ldres,
    int M, int N, int K, int relu)
{
  int bz = blockIdx.z;
  A += (long)bz * sA; B += (long)bz * sB; C += (long)bz * sC;
  int m0 = blockIdx.y * BM, n0 = blockIdx.x * BN;
  __shared__ float As[BK][BM + 4];
  __shared__ float Bs[BK][BN + 4];
  int tid = threadIdx.x;
  int tx = tid & 15, ty = tid >> 4;
  float acc[4][4] = {};
  for (int k0 = 0; k0 < K; k0 += BK) {
#pragma unroll
    for (int it = 0; it < 4; ++it) {
      int e = tid + it * 256;          // 64x16 A tile
      int m = e >> 4, kk = e & 15;
      int gm = m0 + m;
      float val = (gm < M) ? A[(long)gm * lda + k0 + kk] : 0.f;
      As[kk][m] = val;
    }
#pragma unroll
    for (int it = 0; it < 4; ++it) {
      int e = tid + it * 256;          // 16x64 B tile
      int kk = e >> 6, n = e & 63;
      int gn = n0 + n;
      float val = (gn < N) ? B[(long)(k0 + kk) * ldb + gn] : 0.f;
      Bs[kk][n] = val;
    }
    __syncthreads();
#pragma unroll
    for (int kk = 0; kk < BK; ++kk) {
      float a[4], bv[4];
#pragma unroll
      for (int i = 0; i < 4; ++i) a[i] = As[kk][ty * 4 + i];
#pragma unroll
      for (int j = 0; j < 4; ++j) bv[j] = Bs[kk][tx * 4 + j];
#pragma unroll
      for (int i = 0; i < 4; ++i)
#pragma unroll
        for (int j = 0; j < 4; ++j) acc[i][j] += a[i] * bv[j];
    }
    __syncthreads();
  }
#pragma unroll
  for (int i = 0; i < 4; ++i) {
    int gm = m0 + ty * 4 + i;
    if (gm >= M) continue;
#pragma unroll
    for (int j = 0; j < 4; ++j) {
      int gn = n0 + tx * 4 + j;
      if (gn >= N) continue;
      float v = acc[i][j];
      if (bias)  v += bias[gn];
      if (resid) v += resid[(long)gm * ldres + gn];
      if (relu)  v = fmaxf(v, 0.f);
      C[(long)gm * ldc + gn] = v;
    }
  }
}

// ---------------- relative positional encoding table ----------------
// pos[n][2i] = sin((T-1-n)*div_i), pos[n][2i+1] = cos((T-1-n)*div_i)
__global__ __launch_bounds__(256) void pos_kernel(float* __restrict__ pos)
{
  int idx = blockIdx.x * 256 + threadIdx.x;
  if (idx >= NPOS_ * (D_ / 2)) return;
  int n = idx / (D_ / 2), i = idx % (D_ / 2);
  float r = (float)(T_ - 1 - n);
  float div = __expf((float)(2 * i) * (-logf(10000.f) / (float)D_));
  float ang = r * div;
  pos[(long)n * D_ + 2 * i]     = sinf(ang);
  pos[(long)n * D_ + 2 * i + 1] = cosf(ang);
}

// ---------------- attention logits: S[h][t][s] = scale*((q+u).k + (q+v).p_shift) ----------------
// grid (T/16, T/16, H), block (16,16). p row index = s + T-1 - t (always in range).
__global__ __launch_bounds__(256) void attn_logits_kernel(
    const float* __restrict__ Q, const float* __restrict__ K,
    const float* __restrict__ P, const float* __restrict__ posu,
    const float* __restrict__ posv, float* __restrict__ S)
{
  int h = blockIdx.z;
  int t0 = blockIdx.y * 16, s0 = blockIdx.x * 16;
  __shared__ float qu[16][68], qv[16][68], ks[16][68], ps[31][68];
  int tid = threadIdx.y * 16 + threadIdx.x;
#pragma unroll
  for (int it = 0; it < 4; ++it) {
    int e = tid + it * 256;            // 16 rows x 64 cols
    int r = e >> 6, c = e & 63;
    float qval = Q[(long)(t0 + r) * D_ + h * HD_ + c];
    qu[r][c] = qval + posu[h * HD_ + c];
    qv[r][c] = qval + posv[h * HD_ + c];
    ks[r][c] = K[(long)(s0 + r) * D_ + h * HD_ + c];
  }
  int base = s0 - t0 + (T_ - 16);      // s0 + (T-1) - (t0+15)
#pragma unroll
  for (int it = 0; it < 8; ++it) {
    int e = tid + it * 256;            // 31 rows x 64 cols = 1984
    if (e < 31 * 64) {
      int r = e >> 6, c = e & 63;
      ps[r][c] = P[(long)(base + r) * D_ + h * HD_ + c];
    }
  }
  __syncthreads();
  int dt = threadIdx.y, ds = threadIdx.x;
  float acc = 0.f;
#pragma unroll
  for (int d = 0; d < HD_; ++d) {
    acc += qu[dt][d] * ks[ds][d];
    acc += qv[dt][d] * ps[ds + 15 - dt][d];
  }
  S[((long)h * T_ + (t0 + dt)) * T_ + (s0 + ds)] = acc * 0.125f;
}

// ---------------- softmax over last dim (T_), one block per row ----------------
__global__ __launch_bounds__(256) void softmax_kernel(float* __restrict__ S)
{
  __shared__ float sh[8];
  long row = blockIdx.x;
  float* r = S + row * T_;
  float m = -1e30f;
  for (int i = threadIdx.x; i < T_; i += 256) m = fmaxf(m, r[i]);
  m = blockRedMax(m, sh);
  float s = 0.f;
  for (int i = threadIdx.x; i < T_; i += 256) { float e = __expf(r[i] - m); r[i] = e; s += e; }
  s = blockRedSum(s, sh);
  float inv = 1.f / s;
  for (int i = threadIdx.x; i < T_; i += 256) r[i] *= inv;
}

// ---------------- host side ----------------
static inline void launch_gemm(hipStream_t st,
    const float* A, int lda, long sA,
    const float* B, int ldb, long sB,
    float* C, int ldc, long sC,
    const float* bias, const float* resid, int ldres,
    int M, int N, int K, int batch, int relu)
{
  dim3 grid((N + BN - 1) / BN, (M + BM - 1) / BM, batch);
  gemm_kernel<<<grid, 256, 0, st>>>(A, lda, sA, B, ldb, sB, C, ldc, sC,
                                    bias, resid, ldres, M, N, K, relu);
}

extern "C" void kernel_launch(void* const* d_in, const int* in_sizes, int n_in,
                              void* d_out, int out_size, void* d_ws, size_t ws_size,
                              hipStream_t stream) {
  const float* xs       = (const float*)d_in[0];
  const float* embed_W  = (const float*)d_in[1];
  const float* embed_b  = (const float*)d_in[2];
  const float* embed_g  = (const float*)d_in[3];
  const float* embed_bt = (const float*)d_in[4];
  const float* Wq = (const float*)d_in[5];
  const float* bq = (const float*)d_in[6];
  const float* Wk = (const float*)d_in[7];
  const float* bk = (const float*)d_in[8];
  const float* Wv = (const float*)d_in[9];
  const float* bv = (const float*)d_in[10];
  const float* Wo = (const float*)d_in[11];
  const float* bo = (const float*)d_in[12];
  const float* Wp = (const float*)d_in[13];
  const float* pos_u = (const float*)d_in[14];
  const float* pos_v = (const float*)d_in[15];
  const float* ln1_g = (const float*)d_in[16];
  const float* ln1_b = (const float*)d_in[17];
  const float* ln2_g = (const float*)d_in[18];
  const float* ln2_b = (const float*)d_in[19];
  const float* ff_W1 = (const float*)d_in[20];
  const float* ff_b1 = (const float*)d_in[21];
  const float* ff_W2 = (const float*)d_in[22];
  const float* ff_b2 = (const float*)d_in[23];
  const float* after_g = (const float*)d_in[24];
  const float* after_b = (const float*)d_in[25];
  float* out = (float*)d_out;

  float* ws = (float*)d_ws;
  float* bufX  = ws;  ws += (long)T_ * D_;
  float* bufXN = ws;  ws += (long)T_ * D_;
  float* bufQ  = ws;  ws += (long)T_ * D_;
  float* bufK  = ws;  ws += (long)T_ * D_;
  float* bufV  = ws;  ws += (long)T_ * D_;
  float* bufO  = ws;  ws += (long)T_ * D_;
  float* bufPos = ws; ws += (long)NPOS_ * D_;
  float* bufP   = ws; ws += (long)NPOS_ * D_;
  float* bufS   = ws; ws += (long)H_ * T_ * T_;
  float* bufHid = bufS;   // FFN hidden aliases S (disjoint in time)

  // positional encoding table
  {
    int n = NPOS_ * (D_ / 2);
    pos_kernel<<<(n + 255) / 256, 256, 0, stream>>>(bufPos);
  }

  // embed: ReLU(LN(xs@W+b)) * sqrt(D)
  launch_gemm(stream, xs, D_, 0, embed_W, D_, 0, bufO, D_, 0,
              embed_b, nullptr, 0, T_, D_, D_, 1, 0);
  ln_kernel<<<T_, 256, 0, stream>>>(bufO, embed_g, embed_bt, bufX,
                                    1e-5f, 1, 32.0f /* sqrt(1024) */);

  for (int i = 0; i < L_; ++i) {
    const float* wq = Wq + (long)i * D_ * D_;
    const float* wk = Wk + (long)i * D_ * D_;
    const float* wv = Wv + (long)i * D_ * D_;
    const float* wo = Wo + (long)i * D_ * D_;
    const float* wp = Wp + (long)i * D_ * D_;
    const float* w1 = ff_W1 + (long)i * D_ * FF_;
    const float* w2 = ff_W2 + (long)i * FF_ * D_;

    // ln1
    ln_kernel<<<T_, 256, 0, stream>>>(bufX, ln1_g + (long)i * D_, ln1_b + (long)i * D_,
                                      bufXN, 1e-12f, 0, 1.0f);
    // q,k,v,p projections
    launch_gemm(stream, bufXN, D_, 0, wq, D_, 0, bufQ, D_, 0,
                bq + (long)i * D_, nullptr, 0, T_, D_, D_, 1, 0);
    launch_gemm(stream, bufXN, D_, 0, wk, D_, 0, bufK, D_, 0,
                bk + (long)i * D_, nullptr, 0, T_, D_, D_, 1, 0);
    launch_gemm(stream, bufXN, D_, 0, wv, D_, 0, bufV, D_, 0,
                bv + (long)i * D_, nullptr, 0, T_, D_, D_, 1, 0);
    launch_gemm(stream, bufPos, D_, 0, wp, D_, 0, bufP, D_, 0,
                nullptr, nullptr, 0, NPOS_, D_, D_, 1, 0);
    // logits with fused rel-shift
    attn_logits_kernel<<<dim3(T_ / 16, T_ / 16, H_), dim3(16, 16), 0, stream>>>(
        bufQ, bufK, bufP, pos_u + (long)i * D_, pos_v + (long)i * D_, bufS);
    // softmax
    softmax_kernel<<<H_ * T_, 256, 0, stream>>>(bufS);
    // O = attn @ V  (batched per head)
    launch_gemm(stream, bufS, T_, (long)T_ * T_, bufV, D_, HD_,
                bufO, D_, HD_, nullptr, nullptr, 0, T_, HD_, T_, H_, 0);
    // x = x + O @ Wo + bo
    launch_gemm(stream, bufO, D_, 0, wo, D_, 0, bufX, D_, 0,
                bo + (long)i * D_, bufX, D_, T_, D_, D_, 1, 0);
    // ln2
    ln_kernel<<<T_, 256, 0, stream>>>(bufX, ln2_g + (long)i * D_, ln2_b + (long)i * D_,
                                      bufXN, 1e-12f, 0, 1.0f);
    // FFN
    launch_gemm(stream, bufXN, D_, 0, w1, FF_, 0, bufHid, FF_, 0,
                ff_b1 + (long)i * FF_, nullptr, 0, T_, FF_, D_, 1, 1);
    launch_gemm(stream, bufHid, FF_, 0, w2, D_, 0, bufX, D_, 0,
                ff_b2 + (long)i * D_, bufX, D_, T_, D_, FF_, 1, 0);
  }

  // final LN -> out
  ln_kernel<<<T_, 256, 0, stream>>>(bufX, after_g, after_b, out, 1e-5f, 0, 1.0f);
}

// Round 2
// 8853.209 us; speedup vs baseline: 2.4827x; 2.4827x over previous
//
#include <hip/hip_runtime.h>
#include <hip/hip_bf16.h>
#include <math.h>

#define D_    1024
#define H_    16
#define HD_   64
#define L_    14
#define FF_   4096
#define T_    768
#define NPOS_ (2*T_-1)   // 1535

using bf16x8 = __attribute__((ext_vector_type(8))) short;
using f32x4  = __attribute__((ext_vector_type(4))) float;

__device__ inline short f2bf(float f) {
  union { float f; unsigned u; } v; v.f = f;
  unsigned r = v.u + 0x7FFF + ((v.u >> 16) & 1);   // RNE
  return (short)(r >> 16);
}

// ---------------- reduction helpers ----------------
__device__ inline float waveRedSum(float v) {
#pragma unroll
  for (int o = 32; o > 0; o >>= 1) v += __shfl_down(v, o, 64);
  return v;
}
__device__ inline float waveRedMax(float v) {
#pragma unroll
  for (int o = 32; o > 0; o >>= 1) v = fmaxf(v, __shfl_down(v, o, 64));
  return v;
}
__device__ inline float blockRedSum(float v, float* sh) {
  int lane = threadIdx.x & 63, wid = threadIdx.x >> 6;
  v = waveRedSum(v);
  if (lane == 0) sh[wid] = v;
  __syncthreads();
  if (wid == 0) {
    float x = (lane < 4) ? sh[lane] : 0.f;
    x = waveRedSum(x);
    if (lane == 0) sh[0] = x;
  }
  __syncthreads();
  float r = sh[0];
  __syncthreads();
  return r;
}
__device__ inline float blockRedMax(float v, float* sh) {
  int lane = threadIdx.x & 63, wid = threadIdx.x >> 6;
  v = waveRedMax(v);
  if (lane == 0) sh[wid] = v;
  __syncthreads();
  if (wid == 0) {
    float x = (lane < 4) ? sh[lane] : -1e30f;
    x = waveRedMax(x);
    if (lane == 0) sh[0] = x;
  }
  __syncthreads();
  float r = sh[0];
  __syncthreads();
  return r;
}

// ---------------- LayerNorm (one block per row, D_=1024) ----------------
__global__ __launch_bounds__(256) void ln_kernel(
    const float* __restrict__ x, const float* __restrict__ g,
    const float* __restrict__ b, float* __restrict__ y,
    float eps, int relu, float scale)
{
  __shared__ float sh[8];
  long row = blockIdx.x;
  const float* xr = x + row * D_;
  float* yr = y + row * D_;
  float s = 0.f;
  for (int i = threadIdx.x; i < D_; i += 256) s += xr[i];
  float mean = blockRedSum(s, sh) * (1.f / D_);
  float vs = 0.f;
  for (int i = threadIdx.x; i < D_; i += 256) { float d = xr[i] - mean; vs += d * d; }
  float var = blockRedSum(vs, sh) * (1.f / D_);
  float inv = rsqrtf(var + eps);
  for (int i = threadIdx.x; i < D_; i += 256) {
    float v = (xr[i] - mean) * inv * g[i] + b[i];
    if (relu) v = fmaxf(v, 0.f);
    yr[i] = v * scale;
  }
}

// ---------------- bf16 MFMA GEMM: C = A@B (+bias)(+resid)(relu) ----------------
// fp32 operands in global, converted to bf16 during LDS staging.
// BK=64, 256 threads = 4 waves (2x2), wave tile (BM/2)x(BN/2).
// Requires: N % BN == 0, K % 64 == 0 (M may be ragged).
template<int BM, int BN>
__global__ __launch_bounds__(256) void gemm_bf16_kernel(
    const float* __restrict__ A, int lda, long sA,
    const float* __restrict__ B, int ldb, long sB,
    float* C, int ldc, long sC,
    const float* __restrict__ bias, long sBias,
    const float* resid, int ldres,
    int M, int N, int K, int relu)
{
  constexpr int LDT = 72;               // shorts per LDS row (64 + 8 pad, 144 B)
  constexpr int FM = BM / 32;           // frags per wave in M (wave tile BM/2)
  constexpr int FN = BN / 32;
  constexpr int A_IT = BM / 16;         // staging iters (BM*16 float4 / 256)
  constexpr int B_IT = BN / 16;
  constexpr int NSH = (BN == 128) ? 7 : 6;

  __shared__ short As[BM][LDT];
  __shared__ short Bs[BN][LDT];

  int bz = blockIdx.z;
  A += (long)bz * sA; B += (long)bz * sB; C += (long)bz * sC;
  const float* biasz = bias ? bias + (long)bz * sBias : nullptr;

  int m0 = blockIdx.y * BM, n0 = blockIdx.x * BN;
  int tid = threadIdx.x;
  int lane = tid & 63, wid = tid >> 6;
  int wm0 = (wid >> 1) * (BM / 2), wn0 = (wid & 1) * (BN / 2);
  int lr = lane & 15;                   // frag row/col
  int kl = (lane >> 4) * 8;             // frag k offset within 32

  f32x4 acc[FM][FN];
#pragma unroll
  for (int i = 0; i < FM; ++i)
#pragma unroll
    for (int j = 0; j < FN; ++j)
#pragma unroll
      for (int r = 0; r < 4; ++r) acc[i][j][r] = 0.f;

  for (int k0 = 0; k0 < K; k0 += 64) {
    // ---- stage A: BM x 64 (row-major), float4 loads ----
#pragma unroll
    for (int it = 0; it < A_IT; ++it) {
      int f = tid + it * 256;
      int row = f >> 4, c4 = f & 15;
      int gm = m0 + row;
      float4 v = make_float4(0.f, 0.f, 0.f, 0.f);
      if (gm < M) v = *(const float4*)&A[(long)gm * lda + k0 + c4 * 4];
      short4 s;
      s.x = f2bf(v.x); s.y = f2bf(v.y); s.z = f2bf(v.z); s.w = f2bf(v.w);
      *(short4*)&As[row][c4 * 4] = s;
    }
    // ---- stage B transposed: Bs[n][k], column loads ----
#pragma unroll
    for (int it = 0; it < B_IT; ++it) {
      int p = tid + it * 256;
      int n = p & (BN - 1), kq = p >> NSH;
      int gn = n0 + n;
      const float* bp = &B[(long)(k0 + kq * 4) * ldb + gn];
      short4 s;
      s.x = f2bf(bp[0]);
      s.y = f2bf(bp[ldb]);
      s.z = f2bf(bp[2 * (long)ldb]);
      s.w = f2bf(bp[3 * (long)ldb]);
      *(short4*)&Bs[n][kq * 4] = s;
    }
    __syncthreads();
#pragma unroll
    for (int kk = 0; kk < 2; ++kk) {
      bf16x8 a[FM], b[FN];
#pragma unroll
      for (int i = 0; i < FM; ++i)
        a[i] = *(const bf16x8*)&As[wm0 + i * 16 + lr][kk * 32 + kl];
#pragma unroll
      for (int j = 0; j < FN; ++j)
        b[j] = *(const bf16x8*)&Bs[wn0 + j * 16 + lr][kk * 32 + kl];
#pragma unroll
      for (int i = 0; i < FM; ++i)
#pragma unroll
        for (int j = 0; j < FN; ++j)
          acc[i][j] = __builtin_amdgcn_mfma_f32_16x16x32_bf16(a[i], b[j], acc[i][j], 0, 0, 0);
    }
    __syncthreads();
  }
  // ---- epilogue: D col=lane&15, row=(lane>>4)*4+reg ----
#pragma unroll
  for (int i = 0; i < FM; ++i) {
#pragma unroll
    for (int j = 0; j < FN; ++j) {
      int n = n0 + wn0 + j * 16 + lr;
#pragma unroll
      for (int r = 0; r < 4; ++r) {
        int m = m0 + wm0 + i * 16 + (lane >> 4) * 4 + r;
        if (m < M) {
          float v = acc[i][j][r];
          if (biasz) v += biasz[n];
          if (resid) v += resid[(long)m * ldres + n];
          if (relu)  v = fmaxf(v, 0.f);
          C[(long)m * ldc + n] = v;
        }
      }
    }
  }
}

// ---------------- relative positional encoding table ----------------
__global__ __launch_bounds__(256) void pos_kernel(float* __restrict__ pos)
{
  int idx = blockIdx.x * 256 + threadIdx.x;
  if (idx >= NPOS_ * (D_ / 2)) return;
  int n = idx / (D_ / 2), i = idx % (D_ / 2);
  float r = (float)(T_ - 1 - n);
  float div = __expf((float)(2 * i) * (-logf(10000.f) / (float)D_));
  float ang = r * div;
  pos[(long)n * D_ + 2 * i]     = sinf(ang);
  pos[(long)n * D_ + 2 * i + 1] = cosf(ang);
}

// ---------------- attention logits with fused rel-shift ----------------
__global__ __launch_bounds__(256) void attn_logits_kernel(
    const float* __restrict__ Q, const float* __restrict__ K,
    const float* __restrict__ P, const float* __restrict__ posu,
    const float* __restrict__ posv, float* __restrict__ S)
{
  int h = blockIdx.z;
  int t0 = blockIdx.y * 16, s0 = blockIdx.x * 16;
  __shared__ float qu[16][68], qv[16][68], ks[16][68], ps[31][68];
  int tid = threadIdx.y * 16 + threadIdx.x;
#pragma unroll
  for (int it = 0; it < 4; ++it) {
    int e = tid + it * 256;
    int r = e >> 6, c = e & 63;
    float qval = Q[(long)(t0 + r) * D_ + h * HD_ + c];
    qu[r][c] = qval + posu[h * HD_ + c];
    qv[r][c] = qval + posv[h * HD_ + c];
    ks[r][c] = K[(long)(s0 + r) * D_ + h * HD_ + c];
  }
  int base = s0 - t0 + (T_ - 16);
#pragma unroll
  for (int it = 0; it < 8; ++it) {
    int e = tid + it * 256;
    if (e < 31 * 64) {
      int r = e >> 6, c = e & 63;
      ps[r][c] = P[(long)(base + r) * D_ + h * HD_ + c];
    }
  }
  __syncthreads();
  int dt = threadIdx.y, ds = threadIdx.x;
  float acc = 0.f;
#pragma unroll
  for (int d = 0; d < HD_; ++d) {
    acc += qu[dt][d] * ks[ds][d];
    acc += qv[dt][d] * ps[ds + 15 - dt][d];
  }
  S[((long)h * T_ + (t0 + dt)) * T_ + (s0 + ds)] = acc * 0.125f;
}

// ---------------- softmax over last dim ----------------
__global__ __launch_bounds__(256) void softmax_kernel(float* __restrict__ S)
{
  __shared__ float sh[8];
  long row = blockIdx.x;
  float* r = S + row * T_;
  float m = -1e30f;
  for (int i = threadIdx.x; i < T_; i += 256) m = fmaxf(m, r[i]);
  m = blockRedMax(m, sh);
  float s = 0.f;
  for (int i = threadIdx.x; i < T_; i += 256) { float e = __expf(r[i] - m); r[i] = e; s += e; }
  s = blockRedSum(s, sh);
  float inv = 1.f / s;
  for (int i = threadIdx.x; i < T_; i += 256) r[i] *= inv;
}

// ---------------- host side ----------------
template<int BM, int BN>
static inline void launch_gemm(hipStream_t st,
    const float* A, int lda, long sA,
    const float* B, int ldb, long sB,
    float* C, int ldc, long sC,
    const float* bias, long sBias, const float* resid, int ldres,
    int M, int N, int K, int batch, int relu)
{
  dim3 grid(N / BN, (M + BM - 1) / BM, batch);
  gemm_bf16_kernel<BM, BN><<<grid, 256, 0, st>>>(A, lda, sA, B, ldb, sB, C, ldc, sC,
                                                 bias, sBias, resid, ldres, M, N, K, relu);
}

extern "C" void kernel_launch(void* const* d_in, const int* in_sizes, int n_in,
                              void* d_out, int out_size, void* d_ws, size_t ws_size,
                              hipStream_t stream) {
  const float* xs       = (const float*)d_in[0];
  const float* embed_W  = (const float*)d_in[1];
  const float* embed_b  = (const float*)d_in[2];
  const float* embed_g  = (const float*)d_in[3];
  const float* embed_bt = (const float*)d_in[4];
  const float* Wq = (const float*)d_in[5];
  const float* bq = (const float*)d_in[6];
  const float* Wk = (const float*)d_in[7];
  const float* bk = (const float*)d_in[8];
  const float* Wv = (const float*)d_in[9];
  const float* bv = (const float*)d_in[10];
  const float* Wo = (const float*)d_in[11];
  const float* bo = (const float*)d_in[12];
  const float* Wp = (const float*)d_in[13];
  const float* pos_u = (const float*)d_in[14];
  const float* pos_v = (const float*)d_in[15];
  const float* ln1_g = (const float*)d_in[16];
  const float* ln1_b = (const float*)d_in[17];
  const float* ln2_g = (const float*)d_in[18];
  const float* ln2_b = (const float*)d_in[19];
  const float* ff_W1 = (const float*)d_in[20];
  const float* ff_b1 = (const float*)d_in[21];
  const float* ff_W2 = (const float*)d_in[22];
  const float* ff_b2 = (const float*)d_in[23];
  const float* after_g = (const float*)d_in[24];
  const float* after_b = (const float*)d_in[25];
  float* out = (float*)d_out;

  float* ws = (float*)d_ws;
  float* bufX  = ws;  ws += (long)T_ * D_;
  float* bufXN = ws;  ws += (long)T_ * D_;
  float* bufQ  = ws;  ws += (long)T_ * D_;
  float* bufK  = ws;  ws += (long)T_ * D_;
  float* bufV  = ws;  ws += (long)T_ * D_;
  float* bufO  = ws;  ws += (long)T_ * D_;
  float* bufPos = ws; ws += (long)NPOS_ * D_;
  float* bufP   = ws; ws += (long)NPOS_ * D_;
  float* bufS   = ws; ws += (long)H_ * T_ * T_;
  float* bufHid = bufS;   // FFN hidden aliases S (disjoint in time)

  {
    int n = NPOS_ * (D_ / 2);
    pos_kernel<<<(n + 255) / 256, 256, 0, stream>>>(bufPos);
  }

  // embed: ReLU(LN(xs@W+b)) * sqrt(D)
  launch_gemm<64, 128>(stream, xs, D_, 0, embed_W, D_, 0, bufO, D_, 0,
                       embed_b, 0, nullptr, 0, T_, D_, D_, 1, 0);
  ln_kernel<<<T_, 256, 0, stream>>>(bufO, embed_g, embed_bt, bufX,
                                    1e-5f, 1, 32.0f /* sqrt(1024) */);

  for (int i = 0; i < L_; ++i) {
    const float* wq = Wq + (long)i * D_ * D_;
    const float* wk = Wk + (long)i * D_ * D_;
    const float* wv = Wv + (long)i * D_ * D_;
    const float* wo = Wo + (long)i * D_ * D_;
    const float* wp = Wp + (long)i * D_ * D_;
    const float* w1 = ff_W1 + (long)i * D_ * FF_;
    const float* w2 = ff_W2 + (long)i * FF_ * D_;

    ln_kernel<<<T_, 256, 0, stream>>>(bufX, ln1_g + (long)i * D_, ln1_b + (long)i * D_,
                                      bufXN, 1e-12f, 0, 1.0f);
    launch_gemm<64, 128>(stream, bufXN, D_, 0, wq, D_, 0, bufQ, D_, 0,
                         bq + (long)i * D_, 0, nullptr, 0, T_, D_, D_, 1, 0);
    launch_gemm<64, 128>(stream, bufXN, D_, 0, wk, D_, 0, bufK, D_, 0,
                         bk + (long)i * D_, 0, nullptr, 0, T_, D_, D_, 1, 0);
    launch_gemm<64, 128>(stream, bufXN, D_, 0, wv, D_, 0, bufV, D_, 0,
                         bv + (long)i * D_, 0, nullptr, 0, T_, D_, D_, 1, 0);
    launch_gemm<128, 128>(stream, bufPos, D_, 0, wp, D_, 0, bufP, D_, 0,
                          nullptr, 0, nullptr, 0, NPOS_, D_, D_, 1, 0);
    attn_logits_kernel<<<dim3(T_ / 16, T_ / 16, H_), dim3(16, 16), 0, stream>>>(
        bufQ, bufK, bufP, pos_u + (long)i * D_, pos_v + (long)i * D_, bufS);
    softmax_kernel<<<H_ * T_, 256, 0, stream>>>(bufS);
    // O = attn @ V  (batched per head)
    launch_gemm<64, 64>(stream, bufS, T_, (long)T_ * T_, bufV, D_, HD_,
                        bufO, D_, HD_, nullptr, 0, nullptr, 0, T_, HD_, T_, H_, 0);
    // x = x + O @ Wo + bo
    launch_gemm<64, 128>(stream, bufO, D_, 0, wo, D_, 0, bufX, D_, 0,
                         bo + (long)i * D_, 0, bufX, D_, T_, D_, D_, 1, 0);
    ln_kernel<<<T_, 256, 0, stream>>>(bufX, ln2_g + (long)i * D_, ln2_b + (long)i * D_,
                                      bufXN, 1e-12f, 0, 1.0f);
    // FFN
    launch_gemm<128, 128>(stream, bufXN, D_, 0, w1, FF_, 0, bufHid, FF_, 0,
                          ff_b1 + (long)i * FF_, 0, nullptr, 0, T_, FF_, D_, 1, 1);
    launch_gemm<64, 128>(stream, bufHid, FF_, 0, w2, D_, 0, bufX, D_, 0,
                         ff_b2 + (long)i * D_, 0, bufX, D_, T_, D_, FF_, 1, 0);
  }

  ln_kernel<<<T_, 256, 0, stream>>>(bufX, after_g, after_b, out, 1e-5f, 0, 1.0f);
}

// Round 3
// 4648.750 us; speedup vs baseline: 4.7282x; 1.9044x over previous
//
#include <hip/hip_runtime.h>
#include <hip/hip_bf16.h>
#include <math.h>

#define D_    1024
#define H_    16
#define HD_   64
#define L_    14
#define FF_   4096
#define T_    768
#define NPOS_ (2*T_-1)   // 1535

using s16x8 = __attribute__((ext_vector_type(8))) short;
using f32x4 = __attribute__((ext_vector_type(4))) float;

__device__ inline short f2bf(float f) {
  union { float f; unsigned u; } v; v.f = f;
  unsigned r = v.u + 0x7FFF + ((v.u >> 16) & 1);   // RNE
  return (short)(r >> 16);
}
__device__ inline float bf2f(unsigned short u) {
  union { unsigned u; float f; } v; v.u = ((unsigned)u) << 16; return v.f;
}

// ---------------- reduction helpers ----------------
__device__ inline float waveRedSum(float v) {
#pragma unroll
  for (int o = 32; o > 0; o >>= 1) v += __shfl_down(v, o, 64);
  return v;
}
__device__ inline float waveRedMax(float v) {
#pragma unroll
  for (int o = 32; o > 0; o >>= 1) v = fmaxf(v, __shfl_down(v, o, 64));
  return v;
}
__device__ inline float blockRedSum(float v, float* sh) {
  int lane = threadIdx.x & 63, wid = threadIdx.x >> 6;
  v = waveRedSum(v);
  if (lane == 0) sh[wid] = v;
  __syncthreads();
  if (wid == 0) {
    float x = (lane < 4) ? sh[lane] : 0.f;
    x = waveRedSum(x);
    if (lane == 0) sh[0] = x;
  }
  __syncthreads();
  float r = sh[0];
  __syncthreads();
  return r;
}
__device__ inline float blockRedMax(float v, float* sh) {
  int lane = threadIdx.x & 63, wid = threadIdx.x >> 6;
  v = waveRedMax(v);
  if (lane == 0) sh[wid] = v;
  __syncthreads();
  if (wid == 0) {
    float x = (lane < 4) ? sh[lane] : -1e30f;
    x = waveRedMax(x);
    if (lane == 0) sh[0] = x;
  }
  __syncthreads();
  float r = sh[0];
  __syncthreads();
  return r;
}

// ---------------- LayerNorm: fp32 in, fp32-or-bf16 out ----------------
__global__ __launch_bounds__(256) void ln_kernel(
    const float* __restrict__ x, const float* __restrict__ g,
    const float* __restrict__ b, void* __restrict__ y,
    float eps, int relu, float scale, int obf)
{
  __shared__ float sh[8];
  long row = blockIdx.x;
  const float* xr = x + row * D_;
  float s = 0.f;
  for (int i = threadIdx.x; i < D_; i += 256) s += xr[i];
  float mean = blockRedSum(s, sh) * (1.f / D_);
  float vs = 0.f;
  for (int i = threadIdx.x; i < D_; i += 256) { float d = xr[i] - mean; vs += d * d; }
  float var = blockRedSum(vs, sh) * (1.f / D_);
  float inv = rsqrtf(var + eps);
  for (int i = threadIdx.x; i < D_; i += 256) {
    float v = (xr[i] - mean) * inv * g[i] + b[i];
    if (relu) v = fmaxf(v, 0.f);
    v *= scale;
    if (obf) ((unsigned short*)y)[row * D_ + i] = (unsigned short)f2bf(v);
    else     ((float*)y)[row * D_ + i] = v;
  }
}

// ---------------- bf16-A MFMA GEMM, grouped/batched ----------------
// A: bf16 [M][K] (lda elems). B: fp32 or bf16 [K][N]. C: fp32 or bf16.
// z-grid: z in [0, NG*zPerG); g = z/zPerG selects B/C/bias pointer set,
// zb = z%zPerG applies batch strides sAz/sBz/sCz.
// BK=64, 256 threads = 4 waves (2x2), wave tile (BM/2)x(BN/2).
// Requires N % BN == 0, K % 64 == 0; M ragged ok.
template<int BM, int BN, bool BBF16, bool CBF16>
__global__ __launch_bounds__(256) void gemm2_kernel(
    const unsigned short* __restrict__ A, int lda, long sAz,
    const void* __restrict__ B0, const void* __restrict__ B1, const void* __restrict__ B2,
    int ldb, long sBz,
    void* C0, void* C1, void* C2, int ldc, long sCz,
    const float* __restrict__ bias0, const float* __restrict__ bias1,
    const float* __restrict__ bias2,
    const float* __restrict__ resid, int ldres,
    int M, int N, int K, int zPerG, int relu)
{
  constexpr int LDT = 72;              // shorts per LDS row (144 B = 9*16B)
  constexpr int FM = BM / 32, FN = BN / 32;
  constexpr int A_IT = BM / 32;        // BM*8 16B-loads / 256 threads
  constexpr int B_IT = BN / 16;
  constexpr int NSH = (BN == 128) ? 7 : 6;

  __shared__ short As[BM][LDT];
  __shared__ short Bs[BN][LDT];

  int z = blockIdx.z;
  int g = z / zPerG, zb = z - g * zPerG;
  A += (long)zb * sAz;
  const void* Bv = (g == 0) ? B0 : ((g == 1) ? B1 : B2);
  void* Cv       = (g == 0) ? C0 : ((g == 1) ? C1 : C2);
  const float* bias = (g == 0) ? bias0 : ((g == 1) ? bias1 : bias2);
  const float* Bf = (const float*)Bv + zb * sBz;
  const unsigned short* Bh = (const unsigned short*)Bv + zb * sBz;
  float* Cf = (float*)Cv + zb * sCz;
  unsigned short* Ch = (unsigned short*)Cv + zb * sCz;

  int m0 = blockIdx.y * BM, n0 = blockIdx.x * BN;
  int tid = threadIdx.x, lane = tid & 63, wid = tid >> 6;
  int wm0 = (wid >> 1) * (BM / 2), wn0 = (wid & 1) * (BN / 2);
  int lr = lane & 15, kl = (lane >> 4) * 8;

  f32x4 acc[FM][FN];
#pragma unroll
  for (int i = 0; i < FM; ++i)
#pragma unroll
    for (int j = 0; j < FN; ++j)
#pragma unroll
      for (int r = 0; r < 4; ++r) acc[i][j][r] = 0.f;

  for (int k0 = 0; k0 < K; k0 += 64) {
    // ---- stage A: BM x 64 bf16, one 16B load per thread per iter ----
#pragma unroll
    for (int it = 0; it < A_IT; ++it) {
      int f = tid + it * 256;
      int row = f >> 3, c8 = f & 7;
      int gm = m0 + row;
      s16x8 v = {0, 0, 0, 0, 0, 0, 0, 0};
      if (gm < M) v = *(const s16x8*)(A + (long)gm * lda + k0 + c8 * 8);
      *(s16x8*)&As[row][c8 * 8] = v;
    }
    // ---- stage B transposed -> Bs[n][k] ----
#pragma unroll
    for (int it = 0; it < B_IT; ++it) {
      int p = tid + it * 256;
      int n = p & (BN - 1), kq = p >> NSH;
      int gn = n0 + n;
      short4 s;
      if constexpr (BBF16) {
        const unsigned short* bp = Bh + (long)(k0 + kq * 4) * ldb + gn;
        s.x = (short)bp[0]; s.y = (short)bp[ldb];
        s.z = (short)bp[2 * (long)ldb]; s.w = (short)bp[3 * (long)ldb];
      } else {
        const float* bp = Bf + (long)(k0 + kq * 4) * ldb + gn;
        s.x = f2bf(bp[0]); s.y = f2bf(bp[ldb]);
        s.z = f2bf(bp[2 * (long)ldb]); s.w = f2bf(bp[3 * (long)ldb]);
      }
      *(short4*)&Bs[n][kq * 4] = s;
    }
    __syncthreads();
#pragma unroll
    for (int kk = 0; kk < 2; ++kk) {
      s16x8 a[FM], b[FN];
#pragma unroll
      for (int i = 0; i < FM; ++i)
        a[i] = *(const s16x8*)&As[wm0 + i * 16 + lr][kk * 32 + kl];
#pragma unroll
      for (int j = 0; j < FN; ++j)
        b[j] = *(const s16x8*)&Bs[wn0 + j * 16 + lr][kk * 32 + kl];
#pragma unroll
      for (int i = 0; i < FM; ++i)
#pragma unroll
        for (int j = 0; j < FN; ++j)
          acc[i][j] = __builtin_amdgcn_mfma_f32_16x16x32_bf16(a[i], b[j], acc[i][j], 0, 0, 0);
    }
    __syncthreads();
  }
  // ---- epilogue (D: col=lane&15, row=(lane>>4)*4+reg) ----
#pragma unroll
  for (int i = 0; i < FM; ++i) {
#pragma unroll
    for (int j = 0; j < FN; ++j) {
      int n = n0 + wn0 + j * 16 + lr;
      float bv = bias ? bias[n] : 0.f;
#pragma unroll
      for (int r = 0; r < 4; ++r) {
        int m = m0 + wm0 + i * 16 + (lane >> 4) * 4 + r;
        if (m < M) {
          float v = acc[i][j][r] + bv;
          if (resid) v += resid[(long)m * ldres + n];
          if (relu)  v = fmaxf(v, 0.f);
          if constexpr (CBF16) Ch[(long)m * ldc + n] = (unsigned short)f2bf(v);
          else                 Cf[(long)m * ldc + n] = v;
        }
      }
    }
  }
}

// ---------------- fp32 -> bf16 convert ----------------
__global__ __launch_bounds__(256) void f2bf_kernel(
    const float* __restrict__ x, unsigned short* __restrict__ y, int n4)
{
  int i = blockIdx.x * 256 + threadIdx.x;
  if (i >= n4) return;
  float4 v = *(const float4*)&x[i * 4];
  short4 s; s.x = f2bf(v.x); s.y = f2bf(v.y); s.z = f2bf(v.z); s.w = f2bf(v.w);
  *(short4*)&y[i * 4] = s;
}

// ---------------- relative positional encoding table (bf16) ----------------
__global__ __launch_bounds__(256) void pos_kernel(unsigned short* __restrict__ pos)
{
  int idx = blockIdx.x * 256 + threadIdx.x;
  if (idx >= NPOS_ * (D_ / 2)) return;
  int n = idx / (D_ / 2), i = idx % (D_ / 2);
  float r = (float)(T_ - 1 - n);
  float div = __expf((float)(2 * i) * (-logf(10000.f) / (float)D_));
  float ang = r * div;
  pos[(long)n * D_ + 2 * i]     = (unsigned short)f2bf(sinf(ang));
  pos[(long)n * D_ + 2 * i + 1] = (unsigned short)f2bf(cosf(ang));
}

// ---------------- attention logits with fused rel-shift (bf16 in) ----------------
__global__ __launch_bounds__(256) void attn_logits_kernel(
    const unsigned short* __restrict__ Q, const unsigned short* __restrict__ K,
    const unsigned short* __restrict__ P, const float* __restrict__ posu,
    const float* __restrict__ posv, float* __restrict__ S)
{
  int h = blockIdx.z;
  int t0 = blockIdx.y * 16, s0 = blockIdx.x * 16;
  __shared__ float qu[16][68], qv[16][68], ks[16][68], ps[31][68];
  int tid = threadIdx.y * 16 + threadIdx.x;
  {
    int r = tid >> 4, c4 = (tid & 15) * 4;
    ushort4 q4 = *(const ushort4*)&Q[(long)(t0 + r) * D_ + h * HD_ + c4];
    ushort4 k4 = *(const ushort4*)&K[(long)(s0 + r) * D_ + h * HD_ + c4];
    const unsigned short* qp = (const unsigned short*)&q4;
    const unsigned short* kp = (const unsigned short*)&k4;
#pragma unroll
    for (int j = 0; j < 4; ++j) {
      float qf = bf2f(qp[j]);
      qu[r][c4 + j] = qf + posu[h * HD_ + c4 + j];
      qv[r][c4 + j] = qf + posv[h * HD_ + c4 + j];
      ks[r][c4 + j] = bf2f(kp[j]);
    }
  }
  int base = s0 - t0 + (T_ - 16);
#pragma unroll
  for (int it = 0; it < 2; ++it) {
    int e = tid + it * 256;
    if (e < 31 * 16) {
      int r = e >> 4, c4 = (e & 15) * 4;
      ushort4 p4 = *(const ushort4*)&P[(long)(base + r) * D_ + h * HD_ + c4];
      const unsigned short* pp = (const unsigned short*)&p4;
#pragma unroll
      for (int j = 0; j < 4; ++j) ps[r][c4 + j] = bf2f(pp[j]);
    }
  }
  __syncthreads();
  int dt = threadIdx.y, ds = threadIdx.x;
  float acc = 0.f;
#pragma unroll
  for (int d = 0; d < HD_; ++d) {
    acc += qu[dt][d] * ks[ds][d];
    acc += qv[dt][d] * ps[ds + 15 - dt][d];
  }
  S[((long)h * T_ + (t0 + dt)) * T_ + (s0 + ds)] = acc * 0.125f;
}

// ---------------- softmax: fp32 S row -> bf16 P row ----------------
__global__ __launch_bounds__(256) void softmax_kernel(
    float* __restrict__ S, unsigned short* __restrict__ P)
{
  __shared__ float sh[8];
  long row = blockIdx.x;
  float* r = S + row * T_;
  unsigned short* p = P + row * T_;
  float m = -1e30f;
  for (int i = threadIdx.x; i < T_; i += 256) m = fmaxf(m, r[i]);
  m = blockRedMax(m, sh);
  float s = 0.f;
  for (int i = threadIdx.x; i < T_; i += 256) { float e = __expf(r[i] - m); r[i] = e; s += e; }
  s = blockRedSum(s, sh);
  float inv = 1.f / s;
  for (int i = threadIdx.x; i < T_; i += 256) p[i] = (unsigned short)f2bf(r[i] * inv);
}

// ---------------- host side ----------------
extern "C" void kernel_launch(void* const* d_in, const int* in_sizes, int n_in,
                              void* d_out, int out_size, void* d_ws, size_t ws_size,
                              hipStream_t stream) {
  const float* xs       = (const float*)d_in[0];
  const float* embed_W  = (const float*)d_in[1];
  const float* embed_b  = (const float*)d_in[2];
  const float* embed_g  = (const float*)d_in[3];
  const float* embed_bt = (const float*)d_in[4];
  const float* Wq = (const float*)d_in[5];
  const float* bq = (const float*)d_in[6];
  const float* Wk = (const float*)d_in[7];
  const float* bk = (const float*)d_in[8];
  const float* Wv = (const float*)d_in[9];
  const float* bv = (const float*)d_in[10];
  const float* Wo = (const float*)d_in[11];
  const float* bo = (const float*)d_in[12];
  const float* Wp = (const float*)d_in[13];
  const float* pos_u = (const float*)d_in[14];
  const float* pos_v = (const float*)d_in[15];
  const float* ln1_g = (const float*)d_in[16];
  const float* ln1_b = (const float*)d_in[17];
  const float* ln2_g = (const float*)d_in[18];
  const float* ln2_b = (const float*)d_in[19];
  const float* ff_W1 = (const float*)d_in[20];
  const float* ff_b1 = (const float*)d_in[21];
  const float* ff_W2 = (const float*)d_in[22];
  const float* ff_b2 = (const float*)d_in[23];
  const float* after_g = (const float*)d_in[24];
  const float* after_b = (const float*)d_in[25];
  float* out = (float*)d_out;

  // ---- workspace carve (bytes, 256-aligned) ----
  char* w = (char*)d_ws;
  auto carve = [&](size_t bytes) { char* p = w; w += (bytes + 255) & ~(size_t)255; return p; };
  float* bufX  = (float*)carve((size_t)T_ * D_ * 4);
  float* bufT  = (float*)carve((size_t)T_ * D_ * 4);
  float* bufS  = (float*)carve((size_t)H_ * T_ * T_ * 4);
  unsigned short* xsb  = (unsigned short*)carve((size_t)T_ * D_ * 2);
  unsigned short* XNb  = (unsigned short*)carve((size_t)T_ * D_ * 2);
  unsigned short* Qb   = (unsigned short*)carve((size_t)T_ * D_ * 2);
  unsigned short* Kb   = (unsigned short*)carve((size_t)T_ * D_ * 2);
  unsigned short* Vb   = (unsigned short*)carve((size_t)T_ * D_ * 2);
  unsigned short* Ob   = (unsigned short*)carve((size_t)T_ * D_ * 2);
  unsigned short* Hb   = (unsigned short*)carve((size_t)T_ * FF_ * 2);
  unsigned short* Pb   = (unsigned short*)carve((size_t)H_ * T_ * T_ * 2);
  unsigned short* posT = (unsigned short*)carve((size_t)NPOS_ * D_ * 2);
  unsigned short* Pall = (unsigned short*)carve((size_t)L_ * NPOS_ * D_ * 2);

  // pos table (bf16)
  {
    int n = NPOS_ * (D_ / 2);
    pos_kernel<<<(n + 255) / 256, 256, 0, stream>>>(posT);
  }
  // xs -> bf16
  f2bf_kernel<<<(T_ * D_ / 4 + 255) / 256, 256, 0, stream>>>(xs, xsb, T_ * D_ / 4);

  // embed GEMM -> fp32, then LN(relu)*sqrt(D) -> fp32 residual stream
  gemm2_kernel<64, 128, false, false><<<dim3(8, 12, 1), 256, 0, stream>>>(
      xsb, D_, 0, embed_W, nullptr, nullptr, D_, 0,
      bufT, nullptr, nullptr, D_, 0, embed_b, nullptr, nullptr,
      nullptr, 0, T_, D_, D_, 1, 0);
  ln_kernel<<<T_, 256, 0, stream>>>(bufT, embed_g, embed_bt, bufX, 1e-5f, 1, 32.0f, 0);

  // all 14 layers' P = pos @ Wp[i], batched, bf16 out
  gemm2_kernel<64, 128, false, true><<<dim3(8, 24, 14), 256, 0, stream>>>(
      posT, D_, 0, Wp, nullptr, nullptr, D_, (long)D_ * D_,
      Pall, nullptr, nullptr, D_, (long)NPOS_ * D_, nullptr, nullptr, nullptr,
      nullptr, 0, NPOS_, D_, D_, 14, 0);

  for (int i = 0; i < L_; ++i) {
    const float* wq = Wq + (long)i * D_ * D_;
    const float* wk = Wk + (long)i * D_ * D_;
    const float* wv = Wv + (long)i * D_ * D_;
    const float* wo = Wo + (long)i * D_ * D_;
    const float* w1 = ff_W1 + (long)i * D_ * FF_;
    const float* w2 = ff_W2 + (long)i * FF_ * D_;

    ln_kernel<<<T_, 256, 0, stream>>>(bufX, ln1_g + (long)i * D_, ln1_b + (long)i * D_,
                                      XNb, 1e-12f, 0, 1.0f, 1);
    // fused Q,K,V (grouped z = 0,1,2) -> bf16
    gemm2_kernel<64, 128, false, true><<<dim3(8, 12, 3), 256, 0, stream>>>(
        XNb, D_, 0, wq, wk, wv, D_, 0,
        Qb, Kb, Vb, D_, 0,
        bq + (long)i * D_, bk + (long)i * D_, bv + (long)i * D_,
        nullptr, 0, T_, D_, D_, 1, 0);
    attn_logits_kernel<<<dim3(T_ / 16, T_ / 16, H_), dim3(16, 16), 0, stream>>>(
        Qb, Kb, Pall + (long)i * NPOS_ * D_,
        pos_u + (long)i * D_, pos_v + (long)i * D_, bufS);
    softmax_kernel<<<H_ * T_, 256, 0, stream>>>(bufS, Pb);
    // O = P @ V (batched per head) -> bf16
    gemm2_kernel<64, 64, true, true><<<dim3(1, 12, 16), 256, 0, stream>>>(
        Pb, T_, (long)T_ * T_, Vb, nullptr, nullptr, D_, 64,
        Ob, nullptr, nullptr, D_, 64, nullptr, nullptr, nullptr,
        nullptr, 0, T_, HD_, T_, 16, 0);
    // x = x + O @ Wo + bo (fp32 out)
    gemm2_kernel<64, 64, false, false><<<dim3(16, 12, 1), 256, 0, stream>>>(
        Ob, D_, 0, wo, nullptr, nullptr, D_, 0,
        bufX, nullptr, nullptr, D_, 0, bo + (long)i * D_, nullptr, nullptr,
        bufX, D_, T_, D_, D_, 1, 0);
    ln_kernel<<<T_, 256, 0, stream>>>(bufX, ln2_g + (long)i * D_, ln2_b + (long)i * D_,
                                      XNb, 1e-12f, 0, 1.0f, 1);
    // FFN1 -> relu bf16 hidden
    gemm2_kernel<64, 128, false, true><<<dim3(32, 12, 1), 256, 0, stream>>>(
        XNb, D_, 0, w1, nullptr, nullptr, FF_, 0,
        Hb, nullptr, nullptr, FF_, 0, ff_b1 + (long)i * FF_, nullptr, nullptr,
        nullptr, 0, T_, FF_, D_, 1, 1);
    // FFN2 -> fp32 + residual
    gemm2_kernel<64, 64, false, false><<<dim3(16, 12, 1), 256, 0, stream>>>(
        Hb, FF_, 0, w2, nullptr, nullptr, D_, 0,
        bufX, nullptr, nullptr, D_, 0, ff_b2 + (long)i * D_, nullptr, nullptr,
        bufX, D_, T_, FF_, FF_, 1, 0);
  }

  ln_kernel<<<T_, 256, 0, stream>>>(bufX, after_g, after_b, out, 1e-5f, 0, 1.0f, 0);
}

// Round 4
// 4456.878 us; speedup vs baseline: 4.9317x; 1.0431x over previous
//
#include <hip/hip_runtime.h>
#include <hip/hip_bf16.h>
#include <math.h>

#define D_    1024
#define H_    16
#define HD_   64
#define L_    14
#define FF_   4096
#define T_    768
#define NPOS_ (2*T_-1)   // 1535

using s16x8 = __attribute__((ext_vector_type(8))) short;
using f32x4 = __attribute__((ext_vector_type(4))) float;

__device__ inline short f2bf(float f) {
  union { float f; unsigned u; } v; v.f = f;
  unsigned r = v.u + 0x7FFF + ((v.u >> 16) & 1);   // RNE
  return (short)(r >> 16);
}
__device__ inline float bf2f(unsigned short u) {
  union { unsigned u; float f; } v; v.u = ((unsigned)u) << 16; return v.f;
}

// ---------------- reduction helpers ----------------
__device__ inline float waveRedSum(float v) {
#pragma unroll
  for (int o = 32; o > 0; o >>= 1) v += __shfl_down(v, o, 64);
  return v;
}
__device__ inline float waveRedMax(float v) {
#pragma unroll
  for (int o = 32; o > 0; o >>= 1) v = fmaxf(v, __shfl_down(v, o, 64));
  return v;
}
__device__ inline float blockRedSum(float v, float* sh) {
  int lane = threadIdx.x & 63, wid = threadIdx.x >> 6;
  v = waveRedSum(v);
  if (lane == 0) sh[wid] = v;
  __syncthreads();
  if (wid == 0) {
    float x = (lane < 4) ? sh[lane] : 0.f;
    x = waveRedSum(x);
    if (lane == 0) sh[0] = x;
  }
  __syncthreads();
  float r = sh[0];
  __syncthreads();
  return r;
}
__device__ inline float blockRedMax(float v, float* sh) {
  int lane = threadIdx.x & 63, wid = threadIdx.x >> 6;
  v = waveRedMax(v);
  if (lane == 0) sh[wid] = v;
  __syncthreads();
  if (wid == 0) {
    float x = (lane < 4) ? sh[lane] : -1e30f;
    x = waveRedMax(x);
    if (lane == 0) sh[0] = x;
  }
  __syncthreads();
  float r = sh[0];
  __syncthreads();
  return r;
}

// ---------------- LayerNorm: fp32 in, fp32-or-bf16 out ----------------
__global__ __launch_bounds__(256) void ln_kernel(
    const float* __restrict__ x, const float* __restrict__ g,
    const float* __restrict__ b, void* __restrict__ y,
    float eps, int relu, float scale, int obf)
{
  __shared__ float sh[8];
  long row = blockIdx.x;
  const float* xr = x + row * D_;
  float s = 0.f;
  for (int i = threadIdx.x; i < D_; i += 256) s += xr[i];
  float mean = blockRedSum(s, sh) * (1.f / D_);
  float vs = 0.f;
  for (int i = threadIdx.x; i < D_; i += 256) { float d = xr[i] - mean; vs += d * d; }
  float var = blockRedSum(vs, sh) * (1.f / D_);
  float inv = rsqrtf(var + eps);
  for (int i = threadIdx.x; i < D_; i += 256) {
    float v = (xr[i] - mean) * inv * g[i] + b[i];
    if (relu) v = fmaxf(v, 0.f);
    v *= scale;
    if (obf) ((unsigned short*)y)[row * D_ + i] = (unsigned short)f2bf(v);
    else     ((float*)y)[row * D_ + i] = v;
  }
}

// ---------------- bf16-A MFMA GEMM v3: XOR-swizzled LDS, XCD-chunked n-major grid ----
// A: bf16 [M][lda]. B: fp32 or bf16 [K][ldb]. C: fp32 or bf16.
// grid.x = nM*nN (logical id n-major, XCD-chunk swizzled); grid.z = groups*zPerG.
template<int BM, int BN, bool BBF16, bool CBF16>
__global__ __launch_bounds__(256) void gemm3_kernel(
    const unsigned short* __restrict__ A, int lda, long sAz,
    const void* __restrict__ B0, const void* __restrict__ B1, const void* __restrict__ B2,
    int ldb, long sBz,
    void* C0, void* C1, void* C2, int ldc, long sCz,
    const float* __restrict__ bias0, const float* __restrict__ bias1,
    const float* __restrict__ bias2,
    const float* __restrict__ resid, int ldres,
    int M, int N, int K, int zPerG, int relu, int nM)
{
  constexpr int FM = BM / 32, FN = BN / 32;
  constexpr int A_IT = BM / 32;
  constexpr int B_IT = BN / 16;
  constexpr int NSH = (BN == 128) ? 7 : 6;

  __shared__ short As[BM * 64];
  __shared__ short Bs[BN * 64];

  // bijective XCD-chunk swizzle (m204), then n-major decode
  int nb = gridDim.x, bid = blockIdx.x;
  int q = nb >> 3, r = nb & 7, xcd = bid & 7, idx = bid >> 3;
  int lbid = (xcd < r ? xcd * (q + 1) : r * (q + 1) + (xcd - r) * q) + idx;
  int mT = lbid % nM, nT = lbid / nM;
  int m0 = mT * BM, n0 = nT * BN;

  int z = blockIdx.z;
  int g = z / zPerG, zb = z - g * zPerG;
  A += (long)zb * sAz;
  const void* Bv = (g == 0) ? B0 : ((g == 1) ? B1 : B2);
  void* Cv       = (g == 0) ? C0 : ((g == 1) ? C1 : C2);
  const float* bias = (g == 0) ? bias0 : ((g == 1) ? bias1 : bias2);
  const float* Bf = (const float*)Bv + zb * sBz;
  const unsigned short* Bh = (const unsigned short*)Bv + zb * sBz;
  float* Cf = (float*)Cv + zb * sCz;
  unsigned short* Ch = (unsigned short*)Cv + zb * sCz;

  int tid = threadIdx.x, lane = tid & 63, wid = tid >> 6;
  int wm0 = (wid >> 1) * (BM / 2), wn0 = (wid & 1) * (BN / 2);
  int lr = lane & 15, kl = (lane >> 4) * 8;

  f32x4 acc[FM][FN];
#pragma unroll
  for (int i = 0; i < FM; ++i)
#pragma unroll
    for (int j = 0; j < FN; ++j)
#pragma unroll
      for (int rr = 0; rr < 4; ++rr) acc[i][j][rr] = 0.f;

  for (int k0 = 0; k0 < K; k0 += 64) {
    // ---- stage A: BM x 64 bf16, 16B loads, XOR-swizzled LDS ----
#pragma unroll
    for (int it = 0; it < A_IT; ++it) {
      int f = tid + it * 256;
      int row = f >> 3, c8 = f & 7;
      int gm = m0 + row;
      s16x8 v = {0, 0, 0, 0, 0, 0, 0, 0};
      if (gm < M) v = *(const s16x8*)(A + (long)gm * lda + k0 + c8 * 8);
      *(s16x8*)&As[row * 64 + ((c8 ^ (row & 7)) << 3)] = v;
    }
    // ---- stage B transposed -> Bs[n][k], XOR-swizzled ----
#pragma unroll
    for (int it = 0; it < B_IT; ++it) {
      int p = tid + it * 256;
      int n = p & (BN - 1), kq = p >> NSH;
      int gn = n0 + n;
      short4 s;
      if constexpr (BBF16) {
        const unsigned short* bp = Bh + (long)(k0 + kq * 4) * ldb + gn;
        s.x = (short)bp[0]; s.y = (short)bp[ldb];
        s.z = (short)bp[2 * (long)ldb]; s.w = (short)bp[3 * (long)ldb];
      } else {
        const float* bp = Bf + (long)(k0 + kq * 4) * ldb + gn;
        s.x = f2bf(bp[0]); s.y = f2bf(bp[ldb]);
        s.z = f2bf(bp[2 * (long)ldb]); s.w = f2bf(bp[3 * (long)ldb]);
      }
      *(short4*)&Bs[n * 64 + ((kq << 2) ^ ((n & 7) << 3))] = s;
    }
    __syncthreads();
#pragma unroll
    for (int kk = 0; kk < 2; ++kk) {
      s16x8 a[FM], b[FN];
#pragma unroll
      for (int i = 0; i < FM; ++i) {
        int row = wm0 + i * 16 + lr;
        a[i] = *(const s16x8*)&As[row * 64 + ((kk * 32 + kl) ^ ((lr & 7) << 3))];
      }
#pragma unroll
      for (int j = 0; j < FN; ++j) {
        int row = wn0 + j * 16 + lr;
        b[j] = *(const s16x8*)&Bs[row * 64 + ((kk * 32 + kl) ^ ((lr & 7) << 3))];
      }
#pragma unroll
      for (int i = 0; i < FM; ++i)
#pragma unroll
        for (int j = 0; j < FN; ++j)
          acc[i][j] = __builtin_amdgcn_mfma_f32_16x16x32_bf16(a[i], b[j], acc[i][j], 0, 0, 0);
    }
    __syncthreads();
  }
  // ---- epilogue (D: col=lane&15, row=(lane>>4)*4+reg) ----
#pragma unroll
  for (int i = 0; i < FM; ++i) {
#pragma unroll
    for (int j = 0; j < FN; ++j) {
      int n = n0 + wn0 + j * 16 + lr;
      float bv = bias ? bias[n] : 0.f;
#pragma unroll
      for (int rr = 0; rr < 4; ++rr) {
        int m = m0 + wm0 + i * 16 + (lane >> 4) * 4 + rr;
        if (m < M) {
          float v = acc[i][j][rr] + bv;
          if (resid) v += resid[(long)m * ldres + n];
          if (relu)  v = fmaxf(v, 0.f);
          if constexpr (CBF16) Ch[(long)m * ldc + n] = (unsigned short)f2bf(v);
          else                 Cf[(long)m * ldc + n] = v;
        }
      }
    }
  }
}

// ---------------- fp32 -> bf16 convert ----------------
__global__ __launch_bounds__(256) void f2bf_kernel(
    const float* __restrict__ x, unsigned short* __restrict__ y, int n4)
{
  int i = blockIdx.x * 256 + threadIdx.x;
  if (i >= n4) return;
  float4 v = *(const float4*)&x[i * 4];
  short4 s; s.x = f2bf(v.x); s.y = f2bf(v.y); s.z = f2bf(v.z); s.w = f2bf(v.w);
  *(short4*)&y[i * 4] = s;
}

// ---------------- relative positional encoding table (bf16) ----------------
__global__ __launch_bounds__(256) void pos_kernel(unsigned short* __restrict__ pos)
{
  int idx = blockIdx.x * 256 + threadIdx.x;
  if (idx >= NPOS_ * (D_ / 2)) return;
  int n = idx / (D_ / 2), i = idx % (D_ / 2);
  float r = (float)(T_ - 1 - n);
  float div = __expf((float)(2 * i) * (-logf(10000.f) / (float)D_));
  float ang = r * div;
  pos[(long)n * D_ + 2 * i]     = (unsigned short)f2bf(sinf(ang));
  pos[(long)n * D_ + 2 * i + 1] = (unsigned short)f2bf(cosf(ang));
}

// ---------------- MFMA attention logits with fused rel-shift ----------------
// Block: 64x64 output tile for head h. ac = (q+u)@k^T; G = (q+v)@Pslice^T (128 rows);
// bd[r][c] = G[r][c-r+63]. grid (12, 12, 16), 256 threads.
__global__ __launch_bounds__(256) void attn_logits_mfma(
    const unsigned short* __restrict__ Q, const unsigned short* __restrict__ K,
    const unsigned short* __restrict__ P, const float* __restrict__ posu,
    const float* __restrict__ posv, float* __restrict__ S)
{
  __shared__ short smem[20480];          // qu(4096) qv(4096) ks(4096) ps(8192) shorts
  short* qu = smem;
  short* qv = smem + 4096;
  short* ks = smem + 8192;
  short* ps = smem + 12288;
  float* G  = (float*)smem;              // 64x128 fp32 aliases all of the above

  int h = blockIdx.z;
  int t0 = blockIdx.y * 64, s0 = blockIdx.x * 64;
  int base = s0 - t0 + T_ - 64;          // first P row needed
  int tid = threadIdx.x;

  // ---- stage qu, qv, ks (64x64 each) ----
#pragma unroll
  for (int it = 0; it < 4; ++it) {
    int e = tid + it * 256;
    int row = e >> 4, c4 = e & 15;
    int sw = ((c4 << 2) ^ ((row & 7) << 3));
    ushort4 q4 = *(const ushort4*)&Q[(long)(t0 + row) * D_ + h * HD_ + c4 * 4];
    ushort4 k4 = *(const ushort4*)&K[(long)(s0 + row) * D_ + h * HD_ + c4 * 4];
    const unsigned short* qp = (const unsigned short*)&q4;
    short4 su, sv;
    float u0 = posu[h * HD_ + c4 * 4 + 0], u1 = posu[h * HD_ + c4 * 4 + 1];
    float u2 = posu[h * HD_ + c4 * 4 + 2], u3 = posu[h * HD_ + c4 * 4 + 3];
    float v0 = posv[h * HD_ + c4 * 4 + 0], v1 = posv[h * HD_ + c4 * 4 + 1];
    float v2 = posv[h * HD_ + c4 * 4 + 2], v3 = posv[h * HD_ + c4 * 4 + 3];
    su.x = f2bf(bf2f(qp[0]) + u0); su.y = f2bf(bf2f(qp[1]) + u1);
    su.z = f2bf(bf2f(qp[2]) + u2); su.w = f2bf(bf2f(qp[3]) + u3);
    sv.x = f2bf(bf2f(qp[0]) + v0); sv.y = f2bf(bf2f(qp[1]) + v1);
    sv.z = f2bf(bf2f(qp[2]) + v2); sv.w = f2bf(bf2f(qp[3]) + v3);
    *(short4*)&qu[row * 64 + sw] = su;
    *(short4*)&qv[row * 64 + sw] = sv;
    *(short4*)&ks[row * 64 + sw] = *(short4*)&k4;
  }
  // ---- stage ps (128x64) ----
#pragma unroll
  for (int it = 0; it < 8; ++it) {
    int e = tid + it * 256;
    int row = e >> 4, c4 = e & 15;
    int gp = base + row; if (gp > NPOS_ - 1) gp = NPOS_ - 1;
    ushort4 p4 = *(const ushort4*)&P[(long)gp * D_ + h * HD_ + c4 * 4];
    *(short4*)&ps[row * 64 + ((c4 << 2) ^ ((row & 7) << 3))] = *(short4*)&p4;
  }
  __syncthreads();

  int lane = tid & 63, w = tid >> 6;
  int lr = lane & 15, kl = (lane >> 4) * 8;

  s16x8 aqu[2], aqv[2];
#pragma unroll
  for (int kk = 0; kk < 2; ++kk) {
    int row = w * 16 + lr;
    int col = (kk * 32 + kl) ^ ((lr & 7) << 3);
    aqu[kk] = *(const s16x8*)&qu[row * 64 + col];
    aqv[kk] = *(const s16x8*)&qv[row * 64 + col];
  }
  f32x4 acc_ac[4], acc_g[8];
#pragma unroll
  for (int j = 0; j < 4; ++j)
#pragma unroll
    for (int rr = 0; rr < 4; ++rr) acc_ac[j][rr] = 0.f;
#pragma unroll
  for (int j = 0; j < 8; ++j)
#pragma unroll
    for (int rr = 0; rr < 4; ++rr) acc_g[j][rr] = 0.f;

#pragma unroll
  for (int j = 0; j < 4; ++j) {
#pragma unroll
    for (int kk = 0; kk < 2; ++kk) {
      int row = j * 16 + lr;
      s16x8 b = *(const s16x8*)&ks[row * 64 + ((kk * 32 + kl) ^ ((lr & 7) << 3))];
      acc_ac[j] = __builtin_amdgcn_mfma_f32_16x16x32_bf16(aqu[kk], b, acc_ac[j], 0, 0, 0);
    }
  }
#pragma unroll
  for (int j = 0; j < 8; ++j) {
#pragma unroll
    for (int kk = 0; kk < 2; ++kk) {
      int row = j * 16 + lr;
      s16x8 b = *(const s16x8*)&ps[row * 64 + ((kk * 32 + kl) ^ ((lr & 7) << 3))];
      acc_g[j] = __builtin_amdgcn_mfma_f32_16x16x32_bf16(aqv[kk], b, acc_g[j], 0, 0, 0);
    }
  }
  __syncthreads();
  // ---- write G to LDS (row-bit swizzle on 16-col chunks) ----
#pragma unroll
  for (int j = 0; j < 8; ++j) {
#pragma unroll
    for (int rr = 0; rr < 4; ++rr) {
      int row = w * 16 + (lane >> 4) * 4 + rr;
      int col = j * 16 + lr;
      G[row * 128 + (col ^ (((row >> 2) & 3) << 4))] = acc_g[j][rr];
    }
  }
  __syncthreads();
  // ---- combine ac + shifted G, store S ----
#pragma unroll
  for (int j = 0; j < 4; ++j) {
#pragma unroll
    for (int rr = 0; rr < 4; ++rr) {
      int row = w * 16 + (lane >> 4) * 4 + rr;
      int col = j * 16 + lr;
      int gc = col - row + 63;           // in [0,126]
      float bd = G[row * 128 + (gc ^ (((row >> 2) & 3) << 4))];
      S[((long)h * T_ + (t0 + row)) * T_ + (s0 + col)] = (acc_ac[j][rr] + bd) * 0.125f;
    }
  }
}

// ---------------- softmax: fp32 S row -> bf16 P row ----------------
__global__ __launch_bounds__(256) void softmax_kernel(
    float* __restrict__ S, unsigned short* __restrict__ P)
{
  __shared__ float sh[8];
  long row = blockIdx.x;
  float* r = S + row * T_;
  unsigned short* p = P + row * T_;
  float m = -1e30f;
  for (int i = threadIdx.x; i < T_; i += 256) m = fmaxf(m, r[i]);
  m = blockRedMax(m, sh);
  float s = 0.f;
  for (int i = threadIdx.x; i < T_; i += 256) { float e = __expf(r[i] - m); r[i] = e; s += e; }
  s = blockRedSum(s, sh);
  float inv = 1.f / s;
  for (int i = threadIdx.x; i < T_; i += 256) p[i] = (unsigned short)f2bf(r[i] * inv);
}

// ---------------- host side ----------------
extern "C" void kernel_launch(void* const* d_in, const int* in_sizes, int n_in,
                              void* d_out, int out_size, void* d_ws, size_t ws_size,
                              hipStream_t stream) {
  const float* xs       = (const float*)d_in[0];
  const float* embed_W  = (const float*)d_in[1];
  const float* embed_b  = (const float*)d_in[2];
  const float* embed_g  = (const float*)d_in[3];
  const float* embed_bt = (const float*)d_in[4];
  const float* Wq = (const float*)d_in[5];
  const float* bq = (const float*)d_in[6];
  const float* Wk = (const float*)d_in[7];
  const float* bk = (const float*)d_in[8];
  const float* Wv = (const float*)d_in[9];
  const float* bv = (const float*)d_in[10];
  const float* Wo = (const float*)d_in[11];
  const float* bo = (const float*)d_in[12];
  const float* Wp = (const float*)d_in[13];
  const float* pos_u = (const float*)d_in[14];
  const float* pos_v = (const float*)d_in[15];
  const float* ln1_g = (const float*)d_in[16];
  const float* ln1_b = (const float*)d_in[17];
  const float* ln2_g = (const float*)d_in[18];
  const float* ln2_b = (const float*)d_in[19];
  const float* ff_W1 = (const float*)d_in[20];
  const float* ff_b1 = (const float*)d_in[21];
  const float* ff_W2 = (const float*)d_in[22];
  const float* ff_b2 = (const float*)d_in[23];
  const float* after_g = (const float*)d_in[24];
  const float* after_b = (const float*)d_in[25];
  float* out = (float*)d_out;

  char* w = (char*)d_ws;
  auto carve = [&](size_t bytes) { char* p = w; w += (bytes + 255) & ~(size_t)255; return p; };
  float* bufX  = (float*)carve((size_t)T_ * D_ * 4);
  float* bufT  = (float*)carve((size_t)T_ * D_ * 4);
  float* bufS  = (float*)carve((size_t)H_ * T_ * T_ * 4);
  unsigned short* xsb  = (unsigned short*)carve((size_t)T_ * D_ * 2);
  unsigned short* XNb  = (unsigned short*)carve((size_t)T_ * D_ * 2);
  unsigned short* Qb   = (unsigned short*)carve((size_t)T_ * D_ * 2);
  unsigned short* Kb   = (unsigned short*)carve((size_t)T_ * D_ * 2);
  unsigned short* Vb   = (unsigned short*)carve((size_t)T_ * D_ * 2);
  unsigned short* Ob   = (unsigned short*)carve((size_t)T_ * D_ * 2);
  unsigned short* Hb   = (unsigned short*)carve((size_t)T_ * FF_ * 2);
  unsigned short* Pb   = (unsigned short*)carve((size_t)H_ * T_ * T_ * 2);
  unsigned short* posT = (unsigned short*)carve((size_t)NPOS_ * D_ * 2);
  unsigned short* Pall = (unsigned short*)carve((size_t)L_ * NPOS_ * D_ * 2);

  {
    int n = NPOS_ * (D_ / 2);
    pos_kernel<<<(n + 255) / 256, 256, 0, stream>>>(posT);
  }
  f2bf_kernel<<<(T_ * D_ / 4 + 255) / 256, 256, 0, stream>>>(xs, xsb, T_ * D_ / 4);

  // embed GEMM -> fp32, then LN(relu)*sqrt(D)
  gemm3_kernel<64, 128, false, false><<<dim3(96, 1, 1), 256, 0, stream>>>(
      xsb, D_, 0, embed_W, nullptr, nullptr, D_, 0,
      bufT, nullptr, nullptr, D_, 0, embed_b, nullptr, nullptr,
      nullptr, 0, T_, D_, D_, 1, 0, 12);
  ln_kernel<<<T_, 256, 0, stream>>>(bufT, embed_g, embed_bt, bufX, 1e-5f, 1, 32.0f, 0);

  // all 14 layers' P = pos @ Wp[i], batched, bf16 out
  gemm3_kernel<128, 128, false, true><<<dim3(96, 1, 14), 256, 0, stream>>>(
      posT, D_, 0, Wp, nullptr, nullptr, D_, (long)D_ * D_,
      Pall, nullptr, nullptr, D_, (long)NPOS_ * D_, nullptr, nullptr, nullptr,
      nullptr, 0, NPOS_, D_, D_, 14, 0, 12);

  for (int i = 0; i < L_; ++i) {
    const float* wq = Wq + (long)i * D_ * D_;
    const float* wk = Wk + (long)i * D_ * D_;
    const float* wv = Wv + (long)i * D_ * D_;
    const float* wo = Wo + (long)i * D_ * D_;
    const float* w1 = ff_W1 + (long)i * D_ * FF_;
    const float* w2 = ff_W2 + (long)i * FF_ * D_;

    ln_kernel<<<T_, 256, 0, stream>>>(bufX, ln1_g + (long)i * D_, ln1_b + (long)i * D_,
                                      XNb, 1e-12f, 0, 1.0f, 1);
    // fused Q,K,V -> bf16
    gemm3_kernel<64, 128, false, true><<<dim3(96, 1, 3), 256, 0, stream>>>(
        XNb, D_, 0, wq, wk, wv, D_, 0,
        Qb, Kb, Vb, D_, 0,
        bq + (long)i * D_, bk + (long)i * D_, bv + (long)i * D_,
        nullptr, 0, T_, D_, D_, 1, 0, 12);
    attn_logits_mfma<<<dim3(12, 12, 16), 256, 0, stream>>>(
        Qb, Kb, Pall + (long)i * NPOS_ * D_,
        pos_u + (long)i * D_, pos_v + (long)i * D_, bufS);
    softmax_kernel<<<H_ * T_, 256, 0, stream>>>(bufS, Pb);
    // O = P @ V (batched per head) -> bf16
    gemm3_kernel<64, 64, true, true><<<dim3(12, 1, 16), 256, 0, stream>>>(
        Pb, T_, (long)T_ * T_, Vb, nullptr, nullptr, D_, 64,
        Ob, nullptr, nullptr, D_, 64, nullptr, nullptr, nullptr,
        nullptr, 0, T_, HD_, T_, 16, 0, 12);
    // x = x + O @ Wo + bo
    gemm3_kernel<64, 128, false, false><<<dim3(96, 1, 1), 256, 0, stream>>>(
        Ob, D_, 0, wo, nullptr, nullptr, D_, 0,
        bufX, nullptr, nullptr, D_, 0, bo + (long)i * D_, nullptr, nullptr,
        bufX, D_, T_, D_, D_, 1, 0, 12);
    ln_kernel<<<T_, 256, 0, stream>>>(bufX, ln2_g + (long)i * D_, ln2_b + (long)i * D_,
                                      XNb, 1e-12f, 0, 1.0f, 1);
    // FFN1 -> relu bf16 hidden
    gemm3_kernel<128, 128, false, true><<<dim3(192, 1, 1), 256, 0, stream>>>(
        XNb, D_, 0, w1, nullptr, nullptr, FF_, 0,
        Hb, nullptr, nullptr, FF_, 0, ff_b1 + (long)i * FF_, nullptr, nullptr,
        nullptr, 0, T_, FF_, D_, 1, 1, 6);
    // FFN2 -> fp32 + residual
    gemm3_kernel<64, 128, false, false><<<dim3(96, 1, 1), 256, 0, stream>>>(
        Hb, FF_, 0, w2, nullptr, nullptr, D_, 0,
        bufX, nullptr, nullptr, D_, 0, ff_b2 + (long)i * D_, nullptr, nullptr,
        bufX, D_, T_, FF_, FF_, 1, 0, 12);
  }

  ln_kernel<<<T_, 256, 0, stream>>>(bufX, after_g, after_b, out, 1e-5f, 0, 1.0f, 0);
}

// Round 5
// 4103.939 us; speedup vs baseline: 5.3559x; 1.0860x over previous
//
#include <hip/hip_runtime.h>
#include <hip/hip_bf16.h>
#include <math.h>

#define D_    1024
#define H_    16
#define HD_   64
#define L_    14
#define FF_   4096
#define T_    768
#define NPOS_ (2*T_-1)   // 1535

using s16x8 = __attribute__((ext_vector_type(8))) short;
using f32x4 = __attribute__((ext_vector_type(4))) float;

__device__ inline short f2bf(float f) {
  union { float f; unsigned u; } v; v.f = f;
  unsigned r = v.u + 0x7FFF + ((v.u >> 16) & 1);   // RNE
  return (short)(r >> 16);
}
__device__ inline float bf2f(unsigned short u) {
  union { unsigned u; float f; } v; v.u = ((unsigned)u) << 16; return v.f;
}

// ---------------- reduction helpers ----------------
__device__ inline float waveRedSum(float v) {
#pragma unroll
  for (int o = 32; o > 0; o >>= 1) v += __shfl_down(v, o, 64);
  return v;
}
__device__ inline float waveRedMax(float v) {
#pragma unroll
  for (int o = 32; o > 0; o >>= 1) v = fmaxf(v, __shfl_down(v, o, 64));
  return v;
}
__device__ inline float blockRedSum(float v, float* sh) {
  int lane = threadIdx.x & 63, wid = threadIdx.x >> 6;
  v = waveRedSum(v);
  if (lane == 0) sh[wid] = v;
  __syncthreads();
  if (wid == 0) {
    float x = (lane < 4) ? sh[lane] : 0.f;
    x = waveRedSum(x);
    if (lane == 0) sh[0] = x;
  }
  __syncthreads();
  float r = sh[0];
  __syncthreads();
  return r;
}

// ---------------- LayerNorm: fp32 in, fp32-or-bf16 out ----------------
__global__ __launch_bounds__(256) void ln_kernel(
    const float* __restrict__ x, const float* __restrict__ g,
    const float* __restrict__ b, void* __restrict__ y,
    float eps, int relu, float scale, int obf)
{
  __shared__ float sh[8];
  long row = blockIdx.x;
  const float* xr = x + row * D_;
  float s = 0.f;
  for (int i = threadIdx.x; i < D_; i += 256) s += xr[i];
  float mean = blockRedSum(s, sh) * (1.f / D_);
  float vs = 0.f;
  for (int i = threadIdx.x; i < D_; i += 256) { float d = xr[i] - mean; vs += d * d; }
  float var = blockRedSum(vs, sh) * (1.f / D_);
  float inv = rsqrtf(var + eps);
  for (int i = threadIdx.x; i < D_; i += 256) {
    float v = (xr[i] - mean) * inv * g[i] + b[i];
    if (relu) v = fmaxf(v, 0.f);
    v *= scale;
    if (obf) ((unsigned short*)y)[row * D_ + i] = (unsigned short)f2bf(v);
    else     ((float*)y)[row * D_ + i] = v;
  }
}

// ---------------- bf16-A MFMA GEMM v3 (unchanged from R4) ----------------
template<int BM, int BN, bool BBF16, bool CBF16>
__global__ __launch_bounds__(256) void gemm3_kernel(
    const unsigned short* __restrict__ A, int lda, long sAz,
    const void* __restrict__ B0, const void* __restrict__ B1, const void* __restrict__ B2,
    int ldb, long sBz,
    void* C0, void* C1, void* C2, int ldc, long sCz,
    const float* __restrict__ bias0, const float* __restrict__ bias1,
    const float* __restrict__ bias2,
    const float* __restrict__ resid, int ldres,
    int M, int N, int K, int zPerG, int relu, int nM)
{
  constexpr int FM = BM / 32, FN = BN / 32;
  constexpr int A_IT = BM / 32;
  constexpr int B_IT = BN / 16;
  constexpr int NSH = (BN == 128) ? 7 : 6;

  __shared__ short As[BM * 64];
  __shared__ short Bs[BN * 64];

  int nb = gridDim.x, bid = blockIdx.x;
  int q = nb >> 3, r = nb & 7, xcd = bid & 7, idx = bid >> 3;
  int lbid = (xcd < r ? xcd * (q + 1) : r * (q + 1) + (xcd - r) * q) + idx;
  int mT = lbid % nM, nT = lbid / nM;
  int m0 = mT * BM, n0 = nT * BN;

  int z = blockIdx.z;
  int g = z / zPerG, zb = z - g * zPerG;
  A += (long)zb * sAz;
  const void* Bv = (g == 0) ? B0 : ((g == 1) ? B1 : B2);
  void* Cv       = (g == 0) ? C0 : ((g == 1) ? C1 : C2);
  const float* bias = (g == 0) ? bias0 : ((g == 1) ? bias1 : bias2);
  const float* Bf = (const float*)Bv + zb * sBz;
  const unsigned short* Bh = (const unsigned short*)Bv + zb * sBz;
  float* Cf = (float*)Cv + zb * sCz;
  unsigned short* Ch = (unsigned short*)Cv + zb * sCz;

  int tid = threadIdx.x, lane = tid & 63, wid = tid >> 6;
  int wm0 = (wid >> 1) * (BM / 2), wn0 = (wid & 1) * (BN / 2);
  int lr = lane & 15, kl = (lane >> 4) * 8;

  f32x4 acc[FM][FN];
#pragma unroll
  for (int i = 0; i < FM; ++i)
#pragma unroll
    for (int j = 0; j < FN; ++j)
#pragma unroll
      for (int rr = 0; rr < 4; ++rr) acc[i][j][rr] = 0.f;

  for (int k0 = 0; k0 < K; k0 += 64) {
#pragma unroll
    for (int it = 0; it < A_IT; ++it) {
      int f = tid + it * 256;
      int row = f >> 3, c8 = f & 7;
      int gm = m0 + row;
      s16x8 v = {0, 0, 0, 0, 0, 0, 0, 0};
      if (gm < M) v = *(const s16x8*)(A + (long)gm * lda + k0 + c8 * 8);
      *(s16x8*)&As[row * 64 + ((c8 ^ (row & 7)) << 3)] = v;
    }
#pragma unroll
    for (int it = 0; it < B_IT; ++it) {
      int p = tid + it * 256;
      int n = p & (BN - 1), kq = p >> NSH;
      int gn = n0 + n;
      short4 s;
      if constexpr (BBF16) {
        const unsigned short* bp = Bh + (long)(k0 + kq * 4) * ldb + gn;
        s.x = (short)bp[0]; s.y = (short)bp[ldb];
        s.z = (short)bp[2 * (long)ldb]; s.w = (short)bp[3 * (long)ldb];
      } else {
        const float* bp = Bf + (long)(k0 + kq * 4) * ldb + gn;
        s.x = f2bf(bp[0]); s.y = f2bf(bp[ldb]);
        s.z = f2bf(bp[2 * (long)ldb]); s.w = f2bf(bp[3 * (long)ldb]);
      }
      *(short4*)&Bs[n * 64 + ((kq << 2) ^ ((n & 7) << 3))] = s;
    }
    __syncthreads();
#pragma unroll
    for (int kk = 0; kk < 2; ++kk) {
      s16x8 a[FM], b[FN];
#pragma unroll
      for (int i = 0; i < FM; ++i) {
        int row = wm0 + i * 16 + lr;
        a[i] = *(const s16x8*)&As[row * 64 + ((kk * 32 + kl) ^ ((lr & 7) << 3))];
      }
#pragma unroll
      for (int j = 0; j < FN; ++j) {
        int row = wn0 + j * 16 + lr;
        b[j] = *(const s16x8*)&Bs[row * 64 + ((kk * 32 + kl) ^ ((lr & 7) << 3))];
      }
#pragma unroll
      for (int i = 0; i < FM; ++i)
#pragma unroll
        for (int j = 0; j < FN; ++j)
          acc[i][j] = __builtin_amdgcn_mfma_f32_16x16x32_bf16(a[i], b[j], acc[i][j], 0, 0, 0);
    }
    __syncthreads();
  }
#pragma unroll
  for (int i = 0; i < FM; ++i) {
#pragma unroll
    for (int j = 0; j < FN; ++j) {
      int n = n0 + wn0 + j * 16 + lr;
      float bv = bias ? bias[n] : 0.f;
#pragma unroll
      for (int rr = 0; rr < 4; ++rr) {
        int m = m0 + wm0 + i * 16 + (lane >> 4) * 4 + rr;
        if (m < M) {
          float v = acc[i][j][rr] + bv;
          if (resid) v += resid[(long)m * ldres + n];
          if (relu)  v = fmaxf(v, 0.f);
          if constexpr (CBF16) Ch[(long)m * ldc + n] = (unsigned short)f2bf(v);
          else                 Cf[(long)m * ldc + n] = v;
        }
      }
    }
  }
}

// ---------------- fp32 -> bf16 convert ----------------
__global__ __launch_bounds__(256) void f2bf_kernel(
    const float* __restrict__ x, unsigned short* __restrict__ y, int n4)
{
  int i = blockIdx.x * 256 + threadIdx.x;
  if (i >= n4) return;
  float4 v = *(const float4*)&x[i * 4];
  short4 s; s.x = f2bf(v.x); s.y = f2bf(v.y); s.z = f2bf(v.z); s.w = f2bf(v.w);
  *(short4*)&y[i * 4] = s;
}

// ---------------- relative positional encoding table (bf16) ----------------
__global__ __launch_bounds__(256) void pos_kernel(unsigned short* __restrict__ pos)
{
  int idx = blockIdx.x * 256 + threadIdx.x;
  if (idx >= NPOS_ * (D_ / 2)) return;
  int n = idx / (D_ / 2), i = idx % (D_ / 2);
  float r = (float)(T_ - 1 - n);
  float div = __expf((float)(2 * i) * (-logf(10000.f) / (float)D_));
  float ang = r * div;
  pos[(long)n * D_ + 2 * i]     = (unsigned short)f2bf(sinf(ang));
  pos[(long)n * D_ + 2 * i + 1] = (unsigned short)f2bf(cosf(ang));
}

// ---------------- fused flash attention with rel-shift ----------------
// Block: head h (blockIdx.y), 32 q-rows (blockIdx.x*32). Loop s-tiles of 64.
// 4 waves: wr = row-group (16 rows), wc = col-group (32 s-cols / 32 d-cols).
// ac = (q+u)@K^T; G = (q+v)@Ps^T (96 P-rows); bd[r][c] = G[r][c-r+31].
__global__ __launch_bounds__(256) void flash_attn_kernel(
    const unsigned short* __restrict__ Q, const unsigned short* __restrict__ K,
    const unsigned short* __restrict__ V, const unsigned short* __restrict__ P,
    const float* __restrict__ posu, const float* __restrict__ posv,
    unsigned short* __restrict__ O)
{
  __shared__ short Ks[64 * 64];          // K-tile [s][d]
  __shared__ short Vs[64 * 64];          // V-tile transposed [d][s]
  __shared__ short Ps[96 * 64];          // P-rows [j][d]
  __shared__ float Grgn[32 * 99];        // aliased: qu/qv (prologue), G, Pfrag
  __shared__ float mxls[2][32], smls[2][32];

  short* qu = (short*)Grgn;              // 32x64 shorts
  short* qv = qu + 32 * 64;
  float* G  = Grgn;                      // [32][99] fp32
  short* Pf = (short*)Grgn;              // 32x64 shorts (post-gather)

  int h = blockIdx.y;
  int t0 = blockIdx.x * 32;
  int tid = threadIdx.x, lane = tid & 63, w = tid >> 6;
  int wr = w >> 1, wc = w & 1;
  int lr = lane & 15, lg = lane >> 4;
  int kl = lg * 8;
  const float* pu = posu + h * HD_;
  const float* pv = posv + h * HD_;

  // ---- prologue: qu = q+u, qv = q+v (bf16, swizzled) ----
  {
    int row = tid >> 3, c8 = tid & 7;
    s16x8 q8 = *(const s16x8*)(Q + (long)(t0 + row) * D_ + h * HD_ + c8 * 8);
    const unsigned short* qp = (const unsigned short*)&q8;
    s16x8 su, sv;
#pragma unroll
    for (int j = 0; j < 8; ++j) {
      float qf = bf2f(qp[j]);
      su[j] = f2bf(qf + pu[c8 * 8 + j]);
      sv[j] = f2bf(qf + pv[c8 * 8 + j]);
    }
    int sw = row * 64 + ((c8 ^ (row & 7)) << 3);
    *(s16x8*)&qu[sw] = su;
    *(s16x8*)&qv[sw] = sv;
  }
  __syncthreads();
  s16x8 aqu[2], aqv[2];
#pragma unroll
  for (int kk = 0; kk < 2; ++kk) {
    int row = wr * 16 + lr;
    int col = (kk * 32 + kl) ^ ((lr & 7) << 3);
    aqu[kk] = *(const s16x8*)&qu[row * 64 + col];
    aqv[kk] = *(const s16x8*)&qv[row * 64 + col];
  }

  float m_[4], l_[4];
  f32x4 acc_o[2];
#pragma unroll
  for (int rr = 0; rr < 4; ++rr) { m_[rr] = -1e30f; l_[rr] = 0.f; }
#pragma unroll
  for (int j = 0; j < 2; ++j)
#pragma unroll
    for (int rr = 0; rr < 4; ++rr) acc_o[j][rr] = 0.f;

  for (int s0 = 0; s0 < T_; s0 += 64) {
    int base = s0 - t0 + T_ - 32;
    __syncthreads();   // prev-iter LDS consumers done (qu/qv frags, Pf, Vs)
    // ---- stage K (8KB), V^T (8KB), Ps (12KB) ----
#pragma unroll
    for (int it = 0; it < 2; ++it) {
      int f = tid + it * 256;
      int row = f >> 3, c8 = f & 7;
      s16x8 v = *(const s16x8*)(K + (long)(s0 + row) * D_ + h * HD_ + c8 * 8);
      *(s16x8*)&Ks[row * 64 + ((c8 ^ (row & 7)) << 3)] = v;
    }
#pragma unroll
    for (int it = 0; it < 4; ++it) {
      int d = tid & 63, sq = tid >> 6;
      int s = it * 16 + sq * 4;
      const unsigned short* vp = V + (long)(s0 + s) * D_ + h * HD_ + d;
      short4 sv4;
      sv4.x = (short)vp[0];
      sv4.y = (short)vp[D_];
      sv4.z = (short)vp[2 * D_];
      sv4.w = (short)vp[3 * D_];
      *(short4*)&Vs[d * 64 + (s ^ ((d & 7) << 3))] = sv4;
    }
#pragma unroll
    for (int it = 0; it < 3; ++it) {
      int f = tid + it * 256;
      int row = f >> 3, c8 = f & 7;
      int gp = base + row; if (gp > NPOS_ - 1) gp = NPOS_ - 1;
      s16x8 v = *(const s16x8*)(P + (long)gp * D_ + h * HD_ + c8 * 8);
      *(s16x8*)&Ps[row * 64 + ((c8 ^ (row & 7)) << 3)] = v;
    }
    __syncthreads();
    // ---- MFMA: ac (wave: 16 rows x 32 cols), G (16 rows x 48 cols) ----
    f32x4 a_ac[2], a_g[3];
#pragma unroll
    for (int j = 0; j < 2; ++j)
#pragma unroll
      for (int rr = 0; rr < 4; ++rr) a_ac[j][rr] = 0.f;
#pragma unroll
    for (int j = 0; j < 3; ++j)
#pragma unroll
      for (int rr = 0; rr < 4; ++rr) a_g[j][rr] = 0.f;
#pragma unroll
    for (int j = 0; j < 2; ++j)
#pragma unroll
      for (int kk = 0; kk < 2; ++kk) {
        int row = wc * 32 + j * 16 + lr;
        s16x8 b = *(const s16x8*)&Ks[row * 64 + ((kk * 32 + kl) ^ ((lr & 7) << 3))];
        a_ac[j] = __builtin_amdgcn_mfma_f32_16x16x32_bf16(aqu[kk], b, a_ac[j], 0, 0, 0);
      }
#pragma unroll
    for (int j = 0; j < 3; ++j)
#pragma unroll
      for (int kk = 0; kk < 2; ++kk) {
        int row = wc * 48 + j * 16 + lr;
        s16x8 b = *(const s16x8*)&Ps[row * 64 + ((kk * 32 + kl) ^ ((lr & 7) << 3))];
        a_g[j] = __builtin_amdgcn_mfma_f32_16x16x32_bf16(aqv[kk], b, a_g[j], 0, 0, 0);
      }
    // ---- write G ----
#pragma unroll
    for (int j = 0; j < 3; ++j)
#pragma unroll
      for (int rr = 0; rr < 4; ++rr) {
        int row = wr * 16 + lg * 4 + rr;
        int col = wc * 48 + j * 16 + lr;
        G[row * 99 + col] = a_g[j][rr];
      }
    __syncthreads();
    // ---- gather bd, row max (partial, this wave's 32 cols) ----
    float sreg[2][4], pm[4];
#pragma unroll
    for (int rr = 0; rr < 4; ++rr) {
      int row = wr * 16 + lg * 4 + rr;
#pragma unroll
      for (int j = 0; j < 2; ++j) {
        int c = wc * 32 + j * 16 + lr;
        int gc = c - row + 31;
        sreg[j][rr] = (a_ac[j][rr] + G[row * 99 + gc]) * 0.125f;
      }
      pm[rr] = fmaxf(sreg[0][rr], sreg[1][rr]);
    }
#pragma unroll
    for (int o = 1; o < 16; o <<= 1)
#pragma unroll
      for (int rr = 0; rr < 4; ++rr) pm[rr] = fmaxf(pm[rr], __shfl_xor(pm[rr], o, 64));
    if (lr == 0) {
#pragma unroll
      for (int rr = 0; rr < 4; ++rr) mxls[wc][wr * 16 + lg * 4 + rr] = pm[rr];
    }
    __syncthreads();
    // ---- combine max, rescale, exp -> Pf, partial sums ----
    float ps[4];
#pragma unroll
    for (int rr = 0; rr < 4; ++rr) {
      int row = wr * 16 + lg * 4 + rr;
      float mnew = fmaxf(m_[rr], fmaxf(mxls[0][row], mxls[1][row]));
      float sc = __expf(m_[rr] - mnew);
      m_[rr] = mnew;
      l_[rr] *= sc;
      acc_o[0][rr] *= sc;
      acc_o[1][rr] *= sc;
      float p0 = __expf(sreg[0][rr] - mnew);
      float p1 = __expf(sreg[1][rr] - mnew);
      ps[rr] = p0 + p1;
      int c0 = wc * 32 + lr, c1 = wc * 32 + 16 + lr;
      ((unsigned short*)Pf)[row * 64 + (c0 ^ ((row & 7) << 3))] = (unsigned short)f2bf(p0);
      ((unsigned short*)Pf)[row * 64 + (c1 ^ ((row & 7) << 3))] = (unsigned short)f2bf(p1);
    }
#pragma unroll
    for (int o = 1; o < 16; o <<= 1)
#pragma unroll
      for (int rr = 0; rr < 4; ++rr) ps[rr] += __shfl_xor(ps[rr], o, 64);
    if (lr == 0) {
#pragma unroll
      for (int rr = 0; rr < 4; ++rr) smls[wc][wr * 16 + lg * 4 + rr] = ps[rr];
    }
    __syncthreads();
    // ---- l update, O += P @ V ----
#pragma unroll
    for (int rr = 0; rr < 4; ++rr) {
      int row = wr * 16 + lg * 4 + rr;
      l_[rr] += smls[0][row] + smls[1][row];
    }
    s16x8 ap[2];
#pragma unroll
    for (int kk = 0; kk < 2; ++kk) {
      int row = wr * 16 + lr;
      ap[kk] = *(const s16x8*)&((unsigned short*)Pf)[row * 64 + ((kk * 32 + kl) ^ ((lr & 7) << 3))];
    }
#pragma unroll
    for (int j = 0; j < 2; ++j)
#pragma unroll
      for (int kk = 0; kk < 2; ++kk) {
        int row = wc * 32 + j * 16 + lr;
        s16x8 b = *(const s16x8*)&Vs[row * 64 + ((kk * 32 + kl) ^ ((lr & 7) << 3))];
        acc_o[j] = __builtin_amdgcn_mfma_f32_16x16x32_bf16(ap[kk], b, acc_o[j], 0, 0, 0);
      }
  }
  // ---- epilogue: O / l -> bf16 ----
#pragma unroll
  for (int j = 0; j < 2; ++j)
#pragma unroll
    for (int rr = 0; rr < 4; ++rr) {
      int row = t0 + wr * 16 + lg * 4 + rr;
      int col = h * HD_ + wc * 32 + j * 16 + lr;
      O[(long)row * D_ + col] = (unsigned short)f2bf(acc_o[j][rr] / l_[rr]);
    }
}

// ---------------- host side ----------------
extern "C" void kernel_launch(void* const* d_in, const int* in_sizes, int n_in,
                              void* d_out, int out_size, void* d_ws, size_t ws_size,
                              hipStream_t stream) {
  const float* xs       = (const float*)d_in[0];
  const float* embed_W  = (const float*)d_in[1];
  const float* embed_b  = (const float*)d_in[2];
  const float* embed_g  = (const float*)d_in[3];
  const float* embed_bt = (const float*)d_in[4];
  const float* Wq = (const float*)d_in[5];
  const float* bq = (const float*)d_in[6];
  const float* Wk = (const float*)d_in[7];
  const float* bk = (const float*)d_in[8];
  const float* Wv = (const float*)d_in[9];
  const float* bv = (const float*)d_in[10];
  const float* Wo = (const float*)d_in[11];
  const float* bo = (const float*)d_in[12];
  const float* Wp = (const float*)d_in[13];
  const float* pos_u = (const float*)d_in[14];
  const float* pos_v = (const float*)d_in[15];
  const float* ln1_g = (const float*)d_in[16];
  const float* ln1_b = (const float*)d_in[17];
  const float* ln2_g = (const float*)d_in[18];
  const float* ln2_b = (const float*)d_in[19];
  const float* ff_W1 = (const float*)d_in[20];
  const float* ff_b1 = (const float*)d_in[21];
  const float* ff_W2 = (const float*)d_in[22];
  const float* ff_b2 = (const float*)d_in[23];
  const float* after_g = (const float*)d_in[24];
  const float* after_b = (const float*)d_in[25];
  float* out = (float*)d_out;

  char* w = (char*)d_ws;
  auto carve = [&](size_t bytes) { char* p = w; w += (bytes + 255) & ~(size_t)255; return p; };
  float* bufX  = (float*)carve((size_t)T_ * D_ * 4);
  float* bufT  = (float*)carve((size_t)T_ * D_ * 4);
  unsigned short* xsb  = (unsigned short*)carve((size_t)T_ * D_ * 2);
  unsigned short* XNb  = (unsigned short*)carve((size_t)T_ * D_ * 2);
  unsigned short* Qb   = (unsigned short*)carve((size_t)T_ * D_ * 2);
  unsigned short* Kb   = (unsigned short*)carve((size_t)T_ * D_ * 2);
  unsigned short* Vb   = (unsigned short*)carve((size_t)T_ * D_ * 2);
  unsigned short* Ob   = (unsigned short*)carve((size_t)T_ * D_ * 2);
  unsigned short* Hb   = (unsigned short*)carve((size_t)T_ * FF_ * 2);
  unsigned short* posT = (unsigned short*)carve((size_t)NPOS_ * D_ * 2);
  unsigned short* Pall = (unsigned short*)carve((size_t)L_ * NPOS_ * D_ * 2);

  {
    int n = NPOS_ * (D_ / 2);
    pos_kernel<<<(n + 255) / 256, 256, 0, stream>>>(posT);
  }
  f2bf_kernel<<<(T_ * D_ / 4 + 255) / 256, 256, 0, stream>>>(xs, xsb, T_ * D_ / 4);

  // embed GEMM -> fp32, then LN(relu)*sqrt(D)
  gemm3_kernel<64, 128, false, false><<<dim3(96, 1, 1), 256, 0, stream>>>(
      xsb, D_, 0, embed_W, nullptr, nullptr, D_, 0,
      bufT, nullptr, nullptr, D_, 0, embed_b, nullptr, nullptr,
      nullptr, 0, T_, D_, D_, 1, 0, 12);
  ln_kernel<<<T_, 256, 0, stream>>>(bufT, embed_g, embed_bt, bufX, 1e-5f, 1, 32.0f, 0);

  // all 14 layers' P = pos @ Wp[i], batched, bf16 out
  gemm3_kernel<128, 128, false, true><<<dim3(96, 1, 14), 256, 0, stream>>>(
      posT, D_, 0, Wp, nullptr, nullptr, D_, (long)D_ * D_,
      Pall, nullptr, nullptr, D_, (long)NPOS_ * D_, nullptr, nullptr, nullptr,
      nullptr, 0, NPOS_, D_, D_, 14, 0, 12);

  for (int i = 0; i < L_; ++i) {
    const float* wq = Wq + (long)i * D_ * D_;
    const float* wk = Wk + (long)i * D_ * D_;
    const float* wv = Wv + (long)i * D_ * D_;
    const float* wo = Wo + (long)i * D_ * D_;
    const float* w1 = ff_W1 + (long)i * D_ * FF_;
    const float* w2 = ff_W2 + (long)i * FF_ * D_;

    ln_kernel<<<T_, 256, 0, stream>>>(bufX, ln1_g + (long)i * D_, ln1_b + (long)i * D_,
                                      XNb, 1e-12f, 0, 1.0f, 1);
    gemm3_kernel<64, 128, false, true><<<dim3(96, 1, 3), 256, 0, stream>>>(
        XNb, D_, 0, wq, wk, wv, D_, 0,
        Qb, Kb, Vb, D_, 0,
        bq + (long)i * D_, bk + (long)i * D_, bv + (long)i * D_,
        nullptr, 0, T_, D_, D_, 1, 0, 12);
    flash_attn_kernel<<<dim3(T_ / 32, H_), 256, 0, stream>>>(
        Qb, Kb, Vb, Pall + (long)i * NPOS_ * D_,
        pos_u + (long)i * D_, pos_v + (long)i * D_, Ob);
    gemm3_kernel<64, 128, false, false><<<dim3(96, 1, 1), 256, 0, stream>>>(
        Ob, D_, 0, wo, nullptr, nullptr, D_, 0,
        bufX, nullptr, nullptr, D_, 0, bo + (long)i * D_, nullptr, nullptr,
        bufX, D_, T_, D_, D_, 1, 0, 12);
    ln_kernel<<<T_, 256, 0, stream>>>(bufX, ln2_g + (long)i * D_, ln2_b + (long)i * D_,
                                      XNb, 1e-12f, 0, 1.0f, 1);
    gemm3_kernel<128, 128, false, true><<<dim3(192, 1, 1), 256, 0, stream>>>(
        XNb, D_, 0, w1, nullptr, nullptr, FF_, 0,
        Hb, nullptr, nullptr, FF_, 0, ff_b1 + (long)i * FF_, nullptr, nullptr,
        nullptr, 0, T_, FF_, D_, 1, 1, 6);
    gemm3_kernel<64, 128, false, false><<<dim3(96, 1, 1), 256, 0, stream>>>(
        Hb, FF_, 0, w2, nullptr, nullptr, D_, 0,
        bufX, nullptr, nullptr, D_, 0, ff_b2 + (long)i * D_, nullptr, nullptr,
        bufX, D_, T_, FF_, FF_, 1, 0, 12);
  }

  ln_kernel<<<T_, 256, 0, stream>>>(bufX, after_g, after_b, out, 1e-5f, 0, 1.0f, 0);
}

// Round 6
// 2663.760 us; speedup vs baseline: 8.2515x; 1.5407x over previous
//
#include <hip/hip_runtime.h>
#include <hip/hip_bf16.h>
#include <math.h>

#define D_    1024
#define H_    16
#define HD_   64
#define L_    14
#define FF_   4096
#define T_    768
#define NPOS_ (2*T_-1)   // 1535

using s16x8 = __attribute__((ext_vector_type(8))) short;
using f32x4 = __attribute__((ext_vector_type(4))) float;

__device__ inline short f2bf(float f) {
  __hip_bfloat16 h = __float2bfloat16(f);   // compiler can fuse into v_cvt_pk_bf16_f32
  return *reinterpret_cast<short*>(&h);
}
__device__ inline float bf2f(unsigned short u) {
  union { unsigned u; float f; } v; v.u = ((unsigned)u) << 16; return v.f;
}

// ---------------- reduction helpers ----------------
__device__ inline float waveRedSum(float v) {
#pragma unroll
  for (int o = 32; o > 0; o >>= 1) v += __shfl_down(v, o, 64);
  return v;
}
__device__ inline float waveRedMax(float v) {
#pragma unroll
  for (int o = 32; o > 0; o >>= 1) v = fmaxf(v, __shfl_down(v, o, 64));
  return v;
}
__device__ inline float blockRedSum(float v, float* sh) {
  int lane = threadIdx.x & 63, wid = threadIdx.x >> 6;
  v = waveRedSum(v);
  if (lane == 0) sh[wid] = v;
  __syncthreads();
  if (wid == 0) {
    float x = (lane < 4) ? sh[lane] : 0.f;
    x = waveRedSum(x);
    if (lane == 0) sh[0] = x;
  }
  __syncthreads();
  float r = sh[0];
  __syncthreads();
  return r;
}

// ---------------- LayerNorm: fp32 in, fp32-or-bf16 out ----------------
__global__ __launch_bounds__(256) void ln_kernel(
    const float* __restrict__ x, const float* __restrict__ g,
    const float* __restrict__ b, void* __restrict__ y,
    float eps, int relu, float scale, int obf)
{
  __shared__ float sh[8];
  long row = blockIdx.x;
  const float* xr = x + row * D_;
  float s = 0.f;
  for (int i = threadIdx.x; i < D_; i += 256) s += xr[i];
  float mean = blockRedSum(s, sh) * (1.f / D_);
  float vs = 0.f;
  for (int i = threadIdx.x; i < D_; i += 256) { float d = xr[i] - mean; vs += d * d; }
  float var = blockRedSum(vs, sh) * (1.f / D_);
  float inv = rsqrtf(var + eps);
  for (int i = threadIdx.x; i < D_; i += 256) {
    float v = (xr[i] - mean) * inv * g[i] + b[i];
    if (relu) v = fmaxf(v, 0.f);
    v *= scale;
    if (obf) ((unsigned short*)y)[row * D_ + i] = (unsigned short)f2bf(v);
    else     ((float*)y)[row * D_ + i] = v;
  }
}

// ---------------- weight transpose+convert: [K][N] fp32 -> [N][K] bf16 ----------------
__global__ __launch_bounds__(256) void transpose_kernel(
    const float* __restrict__ in, unsigned short* __restrict__ out, int K, int N)
{
  __shared__ unsigned short t[32][33];
  long z = blockIdx.z;
  in  += z * (long)K * N;
  out += z * (long)K * N;
  int n0 = blockIdx.x * 32, k0 = blockIdx.y * 32;
  int tid = threadIdx.x;
  int r = tid >> 3, c4 = (tid & 7) * 4;
  float4 v = *(const float4*)&in[(long)(k0 + r) * N + n0 + c4];
  t[r][c4 + 0] = (unsigned short)f2bf(v.x);
  t[r][c4 + 1] = (unsigned short)f2bf(v.y);
  t[r][c4 + 2] = (unsigned short)f2bf(v.z);
  t[r][c4 + 3] = (unsigned short)f2bf(v.w);
  __syncthreads();
  ushort4 s;
  s.x = t[c4 + 0][r]; s.y = t[c4 + 1][r]; s.z = t[c4 + 2][r]; s.w = t[c4 + 3][r];
  *(ushort4*)&out[(long)(n0 + r) * K + k0 + c4] = s;
}

// ---------------- bf16-A MFMA GEMM v4 ----------------
// A: bf16 [M][lda]. B: BMODE=1 -> bf16 [N][ldb] (transposed, ldb=K);
//                    BMODE=0 -> fp32 [K][ldb] (ldb=N). C: fp32 or bf16.
template<int BM, int BN, int BMODE, bool CBF16>
__global__ __launch_bounds__(256) void gemm4_kernel(
    const unsigned short* __restrict__ A, int lda, long sAz,
    const void* __restrict__ B0, const void* __restrict__ B1, const void* __restrict__ B2,
    int ldb, long sBz,
    void* C0, void* C1, void* C2, int ldc, long sCz,
    const float* __restrict__ bias0, const float* __restrict__ bias1,
    const float* __restrict__ bias2,
    const float* __restrict__ resid, int ldres,
    int M, int N, int K, int zPerG, int relu, int nM)
{
  constexpr int FM = BM / 32, FN = BN / 32;
  constexpr int A_IT = BM / 32;
  constexpr int NSH = (BN == 128) ? 7 : 6;

  __shared__ short As[BM * 64];
  __shared__ short Bs[BN * 64];

  int nb = gridDim.x, bid = blockIdx.x;
  int q = nb >> 3, r = nb & 7, xcd = bid & 7, idx = bid >> 3;
  int lbid = (xcd < r ? xcd * (q + 1) : r * (q + 1) + (xcd - r) * q) + idx;
  int mT = lbid % nM, nT = lbid / nM;
  int m0 = mT * BM, n0 = nT * BN;

  int z = blockIdx.z;
  int g = z / zPerG, zb = z - g * zPerG;
  A += (long)zb * sAz;
  const void* Bv = (g == 0) ? B0 : ((g == 1) ? B1 : B2);
  void* Cv       = (g == 0) ? C0 : ((g == 1) ? C1 : C2);
  const float* bias = (g == 0) ? bias0 : ((g == 1) ? bias1 : bias2);
  const float* Bf = (const float*)Bv + zb * sBz;
  const unsigned short* Bh = (const unsigned short*)Bv + zb * sBz;
  float* Cf = (float*)Cv + zb * sCz;
  unsigned short* Ch = (unsigned short*)Cv + zb * sCz;

  int tid = threadIdx.x, lane = tid & 63, wid = tid >> 6;
  int wm0 = (wid >> 1) * (BM / 2), wn0 = (wid & 1) * (BN / 2);
  int lr = lane & 15, kl = (lane >> 4) * 8;

  f32x4 acc[FM][FN];
#pragma unroll
  for (int i = 0; i < FM; ++i)
#pragma unroll
    for (int j = 0; j < FN; ++j)
#pragma unroll
      for (int rr = 0; rr < 4; ++rr) acc[i][j][rr] = 0.f;

  for (int k0 = 0; k0 < K; k0 += 64) {
    // ---- stage A: BM x 64 bf16 ----
#pragma unroll
    for (int it = 0; it < A_IT; ++it) {
      int f = tid + it * 256;
      int row = f >> 3, c8 = f & 7;
      int gm = m0 + row;
      s16x8 v = {0, 0, 0, 0, 0, 0, 0, 0};
      if (gm < M) v = *(const s16x8*)(A + (long)gm * lda + k0 + c8 * 8);
      *(s16x8*)&As[row * 64 + ((c8 ^ (row & 7)) << 3)] = v;
    }
    // ---- stage B ----
    if constexpr (BMODE == 1) {
      constexpr int B_IT = BN / 32;
#pragma unroll
      for (int it = 0; it < B_IT; ++it) {
        int f = tid + it * 256;
        int row = f >> 3, c8 = f & 7;
        int gn = n0 + row;
        s16x8 v = *(const s16x8*)(Bh + (long)gn * ldb + k0 + c8 * 8);
        *(s16x8*)&Bs[row * 64 + ((c8 ^ (row & 7)) << 3)] = v;
      }
    } else {
      constexpr int B_IT = BN / 16;
#pragma unroll
      for (int it = 0; it < B_IT; ++it) {
        int p = tid + it * 256;
        int n = p & (BN - 1), kq = p >> NSH;
        int gn = n0 + n;
        const float* bp = Bf + (long)(k0 + kq * 4) * ldb + gn;
        short4 s;
        s.x = f2bf(bp[0]); s.y = f2bf(bp[ldb]);
        s.z = f2bf(bp[2 * (long)ldb]); s.w = f2bf(bp[3 * (long)ldb]);
        *(short4*)&Bs[n * 64 + ((kq << 2) ^ ((n & 7) << 3))] = s;
      }
    }
    __syncthreads();
#pragma unroll
    for (int kk = 0; kk < 2; ++kk) {
      s16x8 a[FM], b[FN];
#pragma unroll
      for (int i = 0; i < FM; ++i) {
        int row = wm0 + i * 16 + lr;
        a[i] = *(const s16x8*)&As[row * 64 + ((kk * 32 + kl) ^ ((lr & 7) << 3))];
      }
#pragma unroll
      for (int j = 0; j < FN; ++j) {
        int row = wn0 + j * 16 + lr;
        b[j] = *(const s16x8*)&Bs[row * 64 + ((kk * 32 + kl) ^ ((lr & 7) << 3))];
      }
#pragma unroll
      for (int i = 0; i < FM; ++i)
#pragma unroll
        for (int j = 0; j < FN; ++j)
          acc[i][j] = __builtin_amdgcn_mfma_f32_16x16x32_bf16(a[i], b[j], acc[i][j], 0, 0, 0);
    }
    __syncthreads();
  }
#pragma unroll
  for (int i = 0; i < FM; ++i) {
#pragma unroll
    for (int j = 0; j < FN; ++j) {
      int n = n0 + wn0 + j * 16 + lr;
      float bv = bias ? bias[n] : 0.f;
#pragma unroll
      for (int rr = 0; rr < 4; ++rr) {
        int m = m0 + wm0 + i * 16 + (lane >> 4) * 4 + rr;
        if (m < M) {
          float v = acc[i][j][rr] + bv;
          if (resid) v += resid[(long)m * ldres + n];
          if (relu)  v = fmaxf(v, 0.f);
          if constexpr (CBF16) Ch[(long)m * ldc + n] = (unsigned short)f2bf(v);
          else                 Cf[(long)m * ldc + n] = v;
        }
      }
    }
  }
}

// ---------------- fp32 -> bf16 convert ----------------
__global__ __launch_bounds__(256) void f2bf_kernel(
    const float* __restrict__ x, unsigned short* __restrict__ y, int n4)
{
  int i = blockIdx.x * 256 + threadIdx.x;
  if (i >= n4) return;
  float4 v = *(const float4*)&x[i * 4];
  short4 s; s.x = f2bf(v.x); s.y = f2bf(v.y); s.z = f2bf(v.z); s.w = f2bf(v.w);
  *(short4*)&y[i * 4] = s;
}

// ---------------- relative positional encoding table (bf16) ----------------
__global__ __launch_bounds__(256) void pos_kernel(unsigned short* __restrict__ pos)
{
  int idx = blockIdx.x * 256 + threadIdx.x;
  if (idx >= NPOS_ * (D_ / 2)) return;
  int n = idx / (D_ / 2), i = idx % (D_ / 2);
  float r = (float)(T_ - 1 - n);
  float div = __expf((float)(2 * i) * (-logf(10000.f) / (float)D_));
  float ang = r * div;
  pos[(long)n * D_ + 2 * i]     = (unsigned short)f2bf(sinf(ang));
  pos[(long)n * D_ + 2 * i + 1] = (unsigned short)f2bf(cosf(ang));
}

// ---------------- fused flash attention with rel-shift (unchanged from R5) ----------------
__global__ __launch_bounds__(256) void flash_attn_kernel(
    const unsigned short* __restrict__ Q, const unsigned short* __restrict__ K,
    const unsigned short* __restrict__ V, const unsigned short* __restrict__ P,
    const float* __restrict__ posu, const float* __restrict__ posv,
    unsigned short* __restrict__ O)
{
  __shared__ short Ks[64 * 64];
  __shared__ short Vs[64 * 64];
  __shared__ short Ps[96 * 64];
  __shared__ float Grgn[32 * 99];
  __shared__ float mxls[2][32], smls[2][32];

  short* qu = (short*)Grgn;
  short* qv = qu + 32 * 64;
  float* G  = Grgn;
  short* Pf = (short*)Grgn;

  int h = blockIdx.y;
  int t0 = blockIdx.x * 32;
  int tid = threadIdx.x, lane = tid & 63, w = tid >> 6;
  int wr = w >> 1, wc = w & 1;
  int lr = lane & 15, lg = lane >> 4;
  int kl = lg * 8;
  const float* pu = posu + h * HD_;
  const float* pv = posv + h * HD_;

  {
    int row = tid >> 3, c8 = tid & 7;
    s16x8 q8 = *(const s16x8*)(Q + (long)(t0 + row) * D_ + h * HD_ + c8 * 8);
    const unsigned short* qp = (const unsigned short*)&q8;
    s16x8 su, sv;
#pragma unroll
    for (int j = 0; j < 8; ++j) {
      float qf = bf2f(qp[j]);
      su[j] = f2bf(qf + pu[c8 * 8 + j]);
      sv[j] = f2bf(qf + pv[c8 * 8 + j]);
    }
    int sw = row * 64 + ((c8 ^ (row & 7)) << 3);
    *(s16x8*)&qu[sw] = su;
    *(s16x8*)&qv[sw] = sv;
  }
  __syncthreads();
  s16x8 aqu[2], aqv[2];
#pragma unroll
  for (int kk = 0; kk < 2; ++kk) {
    int row = wr * 16 + lr;
    int col = (kk * 32 + kl) ^ ((lr & 7) << 3);
    aqu[kk] = *(const s16x8*)&qu[row * 64 + col];
    aqv[kk] = *(const s16x8*)&qv[row * 64 + col];
  }

  float m_[4], l_[4];
  f32x4 acc_o[2];
#pragma unroll
  for (int rr = 0; rr < 4; ++rr) { m_[rr] = -1e30f; l_[rr] = 0.f; }
#pragma unroll
  for (int j = 0; j < 2; ++j)
#pragma unroll
    for (int rr = 0; rr < 4; ++rr) acc_o[j][rr] = 0.f;

  for (int s0 = 0; s0 < T_; s0 += 64) {
    int base = s0 - t0 + T_ - 32;
    __syncthreads();
#pragma unroll
    for (int it = 0; it < 2; ++it) {
      int f = tid + it * 256;
      int row = f >> 3, c8 = f & 7;
      s16x8 v = *(const s16x8*)(K + (long)(s0 + row) * D_ + h * HD_ + c8 * 8);
      *(s16x8*)&Ks[row * 64 + ((c8 ^ (row & 7)) << 3)] = v;
    }
#pragma unroll
    for (int it = 0; it < 4; ++it) {
      int d = tid & 63, sq = tid >> 6;
      int s = it * 16 + sq * 4;
      const unsigned short* vp = V + (long)(s0 + s) * D_ + h * HD_ + d;
      short4 sv4;
      sv4.x = (short)vp[0];
      sv4.y = (short)vp[D_];
      sv4.z = (short)vp[2 * D_];
      sv4.w = (short)vp[3 * D_];
      *(short4*)&Vs[d * 64 + (s ^ ((d & 7) << 3))] = sv4;
    }
#pragma unroll
    for (int it = 0; it < 3; ++it) {
      int f = tid + it * 256;
      int row = f >> 3, c8 = f & 7;
      int gp = base + row; if (gp > NPOS_ - 1) gp = NPOS_ - 1;
      s16x8 v = *(const s16x8*)(P + (long)gp * D_ + h * HD_ + c8 * 8);
      *(s16x8*)&Ps[row * 64 + ((c8 ^ (row & 7)) << 3)] = v;
    }
    __syncthreads();
    f32x4 a_ac[2], a_g[3];
#pragma unroll
    for (int j = 0; j < 2; ++j)
#pragma unroll
      for (int rr = 0; rr < 4; ++rr) a_ac[j][rr] = 0.f;
#pragma unroll
    for (int j = 0; j < 3; ++j)
#pragma unroll
      for (int rr = 0; rr < 4; ++rr) a_g[j][rr] = 0.f;
#pragma unroll
    for (int j = 0; j < 2; ++j)
#pragma unroll
      for (int kk = 0; kk < 2; ++kk) {
        int row = wc * 32 + j * 16 + lr;
        s16x8 b = *(const s16x8*)&Ks[row * 64 + ((kk * 32 + kl) ^ ((lr & 7) << 3))];
        a_ac[j] = __builtin_amdgcn_mfma_f32_16x16x32_bf16(aqu[kk], b, a_ac[j], 0, 0, 0);
      }
#pragma unroll
    for (int j = 0; j < 3; ++j)
#pragma unroll
      for (int kk = 0; kk < 2; ++kk) {
        int row = wc * 48 + j * 16 + lr;
        s16x8 b = *(const s16x8*)&Ps[row * 64 + ((kk * 32 + kl) ^ ((lr & 7) << 3))];
        a_g[j] = __builtin_amdgcn_mfma_f32_16x16x32_bf16(aqv[kk], b, a_g[j], 0, 0, 0);
      }
#pragma unroll
    for (int j = 0; j < 3; ++j)
#pragma unroll
      for (int rr = 0; rr < 4; ++rr) {
        int row = wr * 16 + lg * 4 + rr;
        int col = wc * 48 + j * 16 + lr;
        G[row * 99 + col] = a_g[j][rr];
      }
    __syncthreads();
    float sreg[2][4], pm[4];
#pragma unroll
    for (int rr = 0; rr < 4; ++rr) {
      int row = wr * 16 + lg * 4 + rr;
#pragma unroll
      for (int j = 0; j < 2; ++j) {
        int c = wc * 32 + j * 16 + lr;
        int gc = c - row + 31;
        sreg[j][rr] = (a_ac[j][rr] + G[row * 99 + gc]) * 0.125f;
      }
      pm[rr] = fmaxf(sreg[0][rr], sreg[1][rr]);
    }
#pragma unroll
    for (int o = 1; o < 16; o <<= 1)
#pragma unroll
      for (int rr = 0; rr < 4; ++rr) pm[rr] = fmaxf(pm[rr], __shfl_xor(pm[rr], o, 64));
    if (lr == 0) {
#pragma unroll
      for (int rr = 0; rr < 4; ++rr) mxls[wc][wr * 16 + lg * 4 + rr] = pm[rr];
    }
    __syncthreads();
    float ps[4];
#pragma unroll
    for (int rr = 0; rr < 4; ++rr) {
      int row = wr * 16 + lg * 4 + rr;
      float mnew = fmaxf(m_[rr], fmaxf(mxls[0][row], mxls[1][row]));
      float sc = __expf(m_[rr] - mnew);
      m_[rr] = mnew;
      l_[rr] *= sc;
      acc_o[0][rr] *= sc;
      acc_o[1][rr] *= sc;
      float p0 = __expf(sreg[0][rr] - mnew);
      float p1 = __expf(sreg[1][rr] - mnew);
      ps[rr] = p0 + p1;
      int c0 = wc * 32 + lr, c1 = wc * 32 + 16 + lr;
      ((unsigned short*)Pf)[row * 64 + (c0 ^ ((row & 7) << 3))] = (unsigned short)f2bf(p0);
      ((unsigned short*)Pf)[row * 64 + (c1 ^ ((row & 7) << 3))] = (unsigned short)f2bf(p1);
    }
#pragma unroll
    for (int o = 1; o < 16; o <<= 1)
#pragma unroll
      for (int rr = 0; rr < 4; ++rr) ps[rr] += __shfl_xor(ps[rr], o, 64);
    if (lr == 0) {
#pragma unroll
      for (int rr = 0; rr < 4; ++rr) smls[wc][wr * 16 + lg * 4 + rr] = ps[rr];
    }
    __syncthreads();
#pragma unroll
    for (int rr = 0; rr < 4; ++rr) {
      int row = wr * 16 + lg * 4 + rr;
      l_[rr] += smls[0][row] + smls[1][row];
    }
    s16x8 ap[2];
#pragma unroll
    for (int kk = 0; kk < 2; ++kk) {
      int row = wr * 16 + lr;
      ap[kk] = *(const s16x8*)&((unsigned short*)Pf)[row * 64 + ((kk * 32 + kl) ^ ((lr & 7) << 3))];
    }
#pragma unroll
    for (int j = 0; j < 2; ++j)
#pragma unroll
      for (int kk = 0; kk < 2; ++kk) {
        int row = wc * 32 + j * 16 + lr;
        s16x8 b = *(const s16x8*)&Vs[row * 64 + ((kk * 32 + kl) ^ ((lr & 7) << 3))];
        acc_o[j] = __builtin_amdgcn_mfma_f32_16x16x32_bf16(ap[kk], b, acc_o[j], 0, 0, 0);
      }
  }
#pragma unroll
  for (int j = 0; j < 2; ++j)
#pragma unroll
    for (int rr = 0; rr < 4; ++rr) {
      int row = t0 + wr * 16 + lg * 4 + rr;
      int col = h * HD_ + wc * 32 + j * 16 + lr;
      O[(long)row * D_ + col] = (unsigned short)f2bf(acc_o[j][rr] / l_[rr]);
    }
}

// ---------------- host side ----------------
extern "C" void kernel_launch(void* const* d_in, const int* in_sizes, int n_in,
                              void* d_out, int out_size, void* d_ws, size_t ws_size,
                              hipStream_t stream) {
  const float* xs       = (const float*)d_in[0];
  const float* embed_W  = (const float*)d_in[1];
  const float* embed_b  = (const float*)d_in[2];
  const float* embed_g  = (const float*)d_in[3];
  const float* embed_bt = (const float*)d_in[4];
  const float* Wq = (const float*)d_in[5];
  const float* bq = (const float*)d_in[6];
  const float* Wk = (const float*)d_in[7];
  const float* bk = (const float*)d_in[8];
  const float* Wv = (const float*)d_in[9];
  const float* bv = (const float*)d_in[10];
  const float* Wo = (const float*)d_in[11];
  const float* bo = (const float*)d_in[12];
  const float* Wp = (const float*)d_in[13];
  const float* pos_u = (const float*)d_in[14];
  const float* pos_v = (const float*)d_in[15];
  const float* ln1_g = (const float*)d_in[16];
  const float* ln1_b = (const float*)d_in[17];
  const float* ln2_g = (const float*)d_in[18];
  const float* ln2_b = (const float*)d_in[19];
  const float* ff_W1 = (const float*)d_in[20];
  const float* ff_b1 = (const float*)d_in[21];
  const float* ff_W2 = (const float*)d_in[22];
  const float* ff_b2 = (const float*)d_in[23];
  const float* after_g = (const float*)d_in[24];
  const float* after_b = (const float*)d_in[25];
  float* out = (float*)d_out;

  char* w = (char*)d_ws;
  auto carve = [&](size_t bytes) { char* p = w; w += (bytes + 255) & ~(size_t)255; return p; };
  float* bufX  = (float*)carve((size_t)T_ * D_ * 4);
  float* bufT  = (float*)carve((size_t)T_ * D_ * 4);
  unsigned short* xsb  = (unsigned short*)carve((size_t)T_ * D_ * 2);
  unsigned short* XNb  = (unsigned short*)carve((size_t)T_ * D_ * 2);
  unsigned short* Qb   = (unsigned short*)carve((size_t)T_ * D_ * 2);
  unsigned short* Kb   = (unsigned short*)carve((size_t)T_ * D_ * 2);
  unsigned short* Vb   = (unsigned short*)carve((size_t)T_ * D_ * 2);
  unsigned short* Ob   = (unsigned short*)carve((size_t)T_ * D_ * 2);
  unsigned short* Hb   = (unsigned short*)carve((size_t)T_ * FF_ * 2);
  unsigned short* posT = (unsigned short*)carve((size_t)NPOS_ * D_ * 2);
  unsigned short* Pall = (unsigned short*)carve((size_t)L_ * NPOS_ * D_ * 2);
  // bf16-transposed weights (fast path)
  size_t szDD = (size_t)D_ * D_;
  unsigned short* embedWt = (unsigned short*)carve(szDD * 2);
  unsigned short* WqT = (unsigned short*)carve((size_t)L_ * szDD * 2);
  unsigned short* WkT = (unsigned short*)carve((size_t)L_ * szDD * 2);
  unsigned short* WvT = (unsigned short*)carve((size_t)L_ * szDD * 2);
  unsigned short* WoT = (unsigned short*)carve((size_t)L_ * szDD * 2);
  unsigned short* WpT = (unsigned short*)carve((size_t)L_ * szDD * 2);
  unsigned short* W1T = (unsigned short*)carve((size_t)L_ * D_ * FF_ * 2);
  unsigned short* W2T = (unsigned short*)carve((size_t)L_ * D_ * FF_ * 2);
  bool fast = ((size_t)(w - (char*)d_ws) <= ws_size);

  {
    int n = NPOS_ * (D_ / 2);
    pos_kernel<<<(n + 255) / 256, 256, 0, stream>>>(posT);
  }
  f2bf_kernel<<<(T_ * D_ / 4 + 255) / 256, 256, 0, stream>>>(xs, xsb, T_ * D_ / 4);

  if (fast) {
    // ---- weight preconversion: [K][N] fp32 -> [N][K] bf16 ----
    transpose_kernel<<<dim3(32, 32, 1),  256, 0, stream>>>(embed_W, embedWt, D_, D_);
    transpose_kernel<<<dim3(32, 32, L_), 256, 0, stream>>>(Wq, WqT, D_, D_);
    transpose_kernel<<<dim3(32, 32, L_), 256, 0, stream>>>(Wk, WkT, D_, D_);
    transpose_kernel<<<dim3(32, 32, L_), 256, 0, stream>>>(Wv, WvT, D_, D_);
    transpose_kernel<<<dim3(32, 32, L_), 256, 0, stream>>>(Wo, WoT, D_, D_);
    transpose_kernel<<<dim3(32, 32, L_), 256, 0, stream>>>(Wp, WpT, D_, D_);
    transpose_kernel<<<dim3(128, 32, L_), 256, 0, stream>>>(ff_W1, W1T, D_, FF_);
    transpose_kernel<<<dim3(32, 128, L_), 256, 0, stream>>>(ff_W2, W2T, FF_, D_);

    gemm4_kernel<32, 128, 1, false><<<dim3(192, 1, 1), 256, 0, stream>>>(
        xsb, D_, 0, embedWt, nullptr, nullptr, D_, 0,
        bufT, nullptr, nullptr, D_, 0, embed_b, nullptr, nullptr,
        nullptr, 0, T_, D_, D_, 1, 0, 24);
    ln_kernel<<<T_, 256, 0, stream>>>(bufT, embed_g, embed_bt, bufX, 1e-5f, 1, 32.0f, 0);

    gemm4_kernel<128, 64, 1, true><<<dim3(192, 1, 14), 256, 0, stream>>>(
        posT, D_, 0, WpT, nullptr, nullptr, D_, (long)szDD,
        Pall, nullptr, nullptr, D_, (long)NPOS_ * D_, nullptr, nullptr, nullptr,
        nullptr, 0, NPOS_, D_, D_, 14, 0, 12);

    for (int i = 0; i < L_; ++i) {
      ln_kernel<<<T_, 256, 0, stream>>>(bufX, ln1_g + (long)i * D_, ln1_b + (long)i * D_,
                                        XNb, 1e-12f, 0, 1.0f, 1);
      gemm4_kernel<32, 128, 1, true><<<dim3(192, 1, 3), 256, 0, stream>>>(
          XNb, D_, 0, WqT + i * szDD, WkT + i * szDD, WvT + i * szDD, D_, 0,
          Qb, Kb, Vb, D_, 0,
          bq + (long)i * D_, bk + (long)i * D_, bv + (long)i * D_,
          nullptr, 0, T_, D_, D_, 1, 0, 24);
      flash_attn_kernel<<<dim3(T_ / 32, H_), 256, 0, stream>>>(
          Qb, Kb, Vb, Pall + (long)i * NPOS_ * D_,
          pos_u + (long)i * D_, pos_v + (long)i * D_, Ob);
      gemm4_kernel<32, 64, 1, false><<<dim3(384, 1, 1), 256, 0, stream>>>(
          Ob, D_, 0, WoT + i * szDD, nullptr, nullptr, D_, 0,
          bufX, nullptr, nullptr, D_, 0, bo + (long)i * D_, nullptr, nullptr,
          bufX, D_, T_, D_, D_, 1, 0, 24);
      ln_kernel<<<T_, 256, 0, stream>>>(bufX, ln2_g + (long)i * D_, ln2_b + (long)i * D_,
                                        XNb, 1e-12f, 0, 1.0f, 1);
      gemm4_kernel<64, 128, 1, true><<<dim3(384, 1, 1), 256, 0, stream>>>(
          XNb, D_, 0, W1T + (size_t)i * D_ * FF_, nullptr, nullptr, D_, 0,
          Hb, nullptr, nullptr, FF_, 0, ff_b1 + (long)i * FF_, nullptr, nullptr,
          nullptr, 0, T_, FF_, D_, 1, 1, 12);
      gemm4_kernel<32, 64, 1, false><<<dim3(384, 1, 1), 256, 0, stream>>>(
          Hb, FF_, 0, W2T + (size_t)i * D_ * FF_, nullptr, nullptr, FF_, 0,
          bufX, nullptr, nullptr, D_, 0, ff_b2 + (long)i * D_, nullptr, nullptr,
          bufX, D_, T_, FF_, FF_, 1, 0, 24);
    }
  } else {
    // ---- fallback: fp32 B operands, same grids ----
    gemm4_kernel<32, 128, 0, false><<<dim3(192, 1, 1), 256, 0, stream>>>(
        xsb, D_, 0, embed_W, nullptr, nullptr, D_, 0,
        bufT, nullptr, nullptr, D_, 0, embed_b, nullptr, nullptr,
        nullptr, 0, T_, D_, D_, 1, 0, 24);
    ln_kernel<<<T_, 256, 0, stream>>>(bufT, embed_g, embed_bt, bufX, 1e-5f, 1, 32.0f, 0);

    gemm4_kernel<128, 64, 0, true><<<dim3(192, 1, 14), 256, 0, stream>>>(
        posT, D_, 0, Wp, nullptr, nullptr, D_, (long)szDD,
        Pall, nullptr, nullptr, D_, (long)NPOS_ * D_, nullptr, nullptr, nullptr,
        nullptr, 0, NPOS_, D_, D_, 14, 0, 12);

    for (int i = 0; i < L_; ++i) {
      ln_kernel<<<T_, 256, 0, stream>>>(bufX, ln1_g + (long)i * D_, ln1_b + (long)i * D_,
                                        XNb, 1e-12f, 0, 1.0f, 1);
      gemm4_kernel<32, 128, 0, true><<<dim3(192, 1, 3), 256, 0, stream>>>(
          XNb, D_, 0, Wq + i * szDD, Wk + i * szDD, Wv + i * szDD, D_, 0,
          Qb, Kb, Vb, D_, 0,
          bq + (long)i * D_, bk + (long)i * D_, bv + (long)i * D_,
          nullptr, 0, T_, D_, D_, 1, 0, 24);
      flash_attn_kernel<<<dim3(T_ / 32, H_), 256, 0, stream>>>(
          Qb, Kb, Vb, Pall + (long)i * NPOS_ * D_,
          pos_u + (long)i * D_, pos_v + (long)i * D_, Ob);
      gemm4_kernel<32, 64, 0, false><<<dim3(384, 1, 1), 256, 0, stream>>>(
          Ob, D_, 0, Wo + i * szDD, nullptr, nullptr, D_, 0,
          bufX, nullptr, nullptr, D_, 0, bo + (long)i * D_, nullptr, nullptr,
          bufX, D_, T_, D_, D_, 1, 0, 24);
      ln_kernel<<<T_, 256, 0, stream>>>(bufX, ln2_g + (long)i * D_, ln2_b + (long)i * D_,
                                        XNb, 1e-12f, 0, 1.0f, 1);
      gemm4_kernel<64, 128, 0, true><<<dim3(384, 1, 1), 256, 0, stream>>>(
          XNb, D_, 0, ff_W1 + (size_t)i * D_ * FF_, nullptr, nullptr, FF_, 0,
          Hb, nullptr, nullptr, FF_, 0, ff_b1 + (long)i * FF_, nullptr, nullptr,
          nullptr, 0, T_, FF_, D_, 1, 1, 12);
      gemm4_kernel<32, 64, 0, false><<<dim3(384, 1, 1), 256, 0, stream>>>(
          Hb, FF_, 0, ff_W2 + (size_t)i * D_ * FF_, nullptr, nullptr, D_, 0,
          bufX, nullptr, nullptr, D_, 0, ff_b2 + (long)i * D_, nullptr, nullptr,
          bufX, D_, T_, FF_, FF_, 1, 0, 24);
    }
  }

  ln_kernel<<<T_, 256, 0, stream>>>(bufX, after_g, after_b, out, 1e-5f, 0, 1.0f, 0);
}